// Round 15
// baseline (250.844 us; speedup 1.0000x reference)
//
#include <hip/hip_runtime.h>
#include <math.h>

// ---------------- problem constants ----------------
constexpr int HD = 48, WD = 48, LQ = HD * WD;     // 2304 downsampled positions / patches
constexpr int CC = 64;                             // channels
constexpr int HH = 96, WW = 96, NPIX = HH * WW;    // 9216 full-res pixels
constexpr int KC = CC * 9;                         // 576 im2col K
constexpr int ND = 16 * CC;                        // 1024 deconv GEMM N
constexpr long LL = (long)LQ * LQ;                 // 5,308,416

typedef __attribute__((ext_vector_type(8))) short bf16x8;
typedef __attribute__((ext_vector_type(4))) float f32x4;
typedef __attribute__((ext_vector_type(8))) int i32x8;
// 4-byte-aligned float4 for unaligned-base tap loads (global unaligned access OK)
typedef float f32x4u __attribute__((ext_vector_type(4), aligned(4)));

static __device__ __forceinline__ float eluf(float x) {
  return x > 0.f ? x : expm1f(x);
}
static __device__ __forceinline__ unsigned short f2bf(float x) {
  unsigned u = __float_as_uint(x);
  unsigned r = (u + 0x7fffu + ((u >> 16) & 1u)) >> 16;
  return (unsigned short)r;
}
static __device__ __forceinline__ float bf2f(unsigned short h) {
  return __uint_as_float((unsigned)h << 16);
}
// bijective XCD swizzle (m204): consecutive outputs land on one XCD
static __device__ __forceinline__ int xcd_swz(int bid, int nwg) {
  int q = nwg >> 3, r8 = nwg & 7;
  int xcd = bid & 7, idx = bid >> 3;
  return (xcd < r8 ? xcd * (q + 1) : r8 * (q + 1) + (xcd - r8) * q) + idx;
}

// ---------------- pack downsampled f/b as [q][c] ----------------
__global__ void pack_fdbd(const float* __restrict__ f, const float* __restrict__ bimg,
                          float* __restrict__ fdt, float* __restrict__ bdt, int batchBase) {
  int b = batchBase + blockIdx.z;
  int idx = blockIdx.x * 256 + threadIdx.x;      // < CC*LQ = 147456
  int c = idx / LQ, r = idx % LQ;
  int y = r / WD, x = r % WD;
  long src = ((long)(b * CC + c) * HH + 2 * y) * WW + 2 * x;
  long dst = (long)b * LQ * CC + (long)r * CC + c;
  fdt[dst] = f[src];
  bdt[dst] = bimg[src];
}

// ---------------- per-position squared-channel sums ----------------
__global__ void sq_kernel(const float* __restrict__ bdt, float* __restrict__ sq, int batchBase) {
  int b = batchBase + blockIdx.z;
  int q = blockIdx.x;
  int c = threadIdx.x;                            // 64 = one wave
  float v = bdt[(long)b * LQ * CC + (long)q * CC + c];
  v *= v;
  for (int off = 32; off; off >>= 1) v += __shfl_down(v, off);
  if (c == 0) sq[b * LQ + q] = v;
}

// ---------------- inv patch norms + valid-mask mm ----------------
__global__ void prep_l(const float* __restrict__ sq, const float* __restrict__ mask,
                       float* __restrict__ invn, float* __restrict__ mmb, int batchBase) {
  int b = batchBase + blockIdx.z;
  int l = blockIdx.x * 256 + threadIdx.x;        // < LQ exactly (grid 9)
  int li = l / WD, lj = l % WD;
  float ss = 0.f, mv = 0.f;
  for (int du = -1; du <= 1; ++du)
    for (int dv = -1; dv <= 1; ++dv) {
      int yy = li + du, xx = lj + dv;
      if ((unsigned)yy < (unsigned)HD && (unsigned)xx < (unsigned)WD) {
        ss += sq[b * LQ + yy * WD + xx];
        mv += mask[b * LQ + yy * WD + xx];
      }
    }
  invn[b * LQ + l] = 1.f / fmaxf(sqrtf(ss), 1e-4f);
  mmb[b * LQ + l] = (mv == 0.f) ? 1.f : 0.f;
}

// ---------------- fp32 Gram GEMM: G = fdt * bdt^T, K=64 single-stage ---------------
__global__ __launch_bounds__(256) void gram_gemm(
    const float* __restrict__ A, const float* __restrict__ B, float* __restrict__ C,
    long sA, long sB, long sC) {
  constexpr int BM = 128, BN = 128, TM = 8, BK = 64;
  __shared__ float As[BK][BM];
  __shared__ float Bs[BK][BN];
  const int z = blockIdx.z;
  A += (long)z * sA;
  B += (long)z * sB;
  C += (long)z * sC;
  const int tn0 = blockIdx.x * BN;
  const int tm0 = blockIdx.y * BM;
  const int tid = threadIdx.x;
  const int tx = tid & 15, ty = tid >> 4;
#pragma unroll
  for (int s = 0; s < 8; ++s) {
    int idx = tid + s * 256;
    int row = idx & 127;
    int k4 = idx >> 7;
    float4 v = *(const float4*)(A + (long)(tm0 + row) * CC + k4 * 4);
    As[k4 * 4 + 0][row] = v.x;
    As[k4 * 4 + 1][row] = v.y;
    As[k4 * 4 + 2][row] = v.z;
    As[k4 * 4 + 3][row] = v.w;
    float4 u = *(const float4*)(B + (long)(tn0 + row) * CC + k4 * 4);
    Bs[k4 * 4 + 0][row] = u.x;
    Bs[k4 * 4 + 1][row] = u.y;
    Bs[k4 * 4 + 2][row] = u.z;
    Bs[k4 * 4 + 3][row] = u.w;
  }
  __syncthreads();
  float acc[TM][8];
#pragma unroll
  for (int m = 0; m < TM; ++m)
#pragma unroll
    for (int n = 0; n < 8; ++n) acc[m][n] = 0.f;
#pragma unroll 4
  for (int kk = 0; kk < BK; ++kk) {
    float a[TM], b[8];
    *(float4*)&a[0] = *(const float4*)&As[kk][ty * TM];
    *(float4*)&a[4] = *(const float4*)&As[kk][ty * TM + 4];
    *(float4*)&b[0] = *(const float4*)&Bs[kk][tx * 4];        // 16 lanes x 16B stride
    *(float4*)&b[4] = *(const float4*)&Bs[kk][64 + tx * 4];   // -> conflict-free
#pragma unroll
    for (int m = 0; m < TM; ++m)
#pragma unroll
      for (int n = 0; n < 8; ++n) acc[m][n] = fmaf(a[m], b[n], acc[m][n]);
  }
#pragma unroll
  for (int m = 0; m < TM; ++m) {
    long row = tm0 + ty * TM + m;
    *(float4*)(C + row * LQ + tn0 + tx * 4) =
        make_float4(acc[m][0], acc[m][1], acc[m][2], acc[m][3]);
    *(float4*)(C + row * LQ + tn0 + 64 + tx * 4) =
        make_float4(acc[m][4], acc[m][5], acc[m][6], acc[m][7]);
  }
}

// ---------------- deconv MX-fp8 MFMA GEMM, 64x128 tile, BK=128, 2-phase dbuf -------
__global__ __launch_bounds__(256) void gemm_deconv(
    const unsigned char* __restrict__ A, const unsigned char* __restrict__ B,
    unsigned short* __restrict__ C, int K, long sA, long sB, long sC, int tilesY) {
  int swz = xcd_swz(blockIdx.x, gridDim.x);
  int perz = tilesY * 8;
  int z = swz / perz, t2 = swz - z * perz;
  int ty = t2 >> 3, tx = t2 & 7;
  A += (long)z * sA;
  B += (long)z * sB;
  C += (long)z * sC;
  const int tid = threadIdx.x;
  const int wave = tid >> 6, lane = tid & 63;
  const int wr = wave >> 1, wc = wave & 1;
  const int tm0 = ty * 64, tn0 = tx * 128;
  __shared__ unsigned char As[2][64 * 128];      // 8KB/buf
  __shared__ unsigned char Bs[2][128 * 128];     // 16KB/buf
  f32x4 acc[2][4] = {};

  int aRow[2], aCol[2], aDst[2];
#pragma unroll
  for (int t = 0; t < 2; ++t) {
    int o = t * 4096 + tid * 16;
    int row = o >> 7;
    aRow[t] = row;
    aCol[t] = (o & 127) ^ ((row & 7) << 4);      // byte == element offset
    aDst[t] = t * 4096 + wave * 1024;            // byte, wave-uniform
  }
  int bRow[4], bCol[4], bDst[4];
#pragma unroll
  for (int t = 0; t < 4; ++t) {
    int o = t * 4096 + tid * 16;
    int row = o >> 7;
    bRow[t] = row;
    bCol[t] = (o & 127) ^ ((row & 7) << 4);
    bDst[t] = t * 4096 + wave * 1024;
  }

#define STAGE_DC(buf, k0)                                                             \
  do {                                                                                \
    _Pragma("unroll") for (int t = 0; t < 2; ++t)                                     \
        __builtin_amdgcn_global_load_lds(                                             \
            (const __attribute__((address_space(1))) void*)(A +                       \
                (long)(tm0 + aRow[t]) * K + (k0) + aCol[t]),                          \
            (__attribute__((address_space(3))) void*)((char*)&As[buf][0] + aDst[t]),  \
            16, 0, 0);                                                                \
    _Pragma("unroll") for (int t = 0; t < 4; ++t)                                     \
        __builtin_amdgcn_global_load_lds(                                             \
            (const __attribute__((address_space(1))) void*)(B +                       \
                (long)(tn0 + bRow[t]) * K + (k0) + bCol[t]),                          \
            (__attribute__((address_space(3))) void*)((char*)&Bs[buf][0] + bDst[t]),  \
            16, 0, 0);                                                                \
  } while (0)

  STAGE_DC(0, 0);
  asm volatile("s_waitcnt vmcnt(0)");
  __builtin_amdgcn_s_barrier();
  int cur = 0;
  for (int k0 = 0; k0 < K; k0 += 128) {          // 18 steps
    if (k0 + 128 < K) STAGE_DC(cur ^ 1, k0 + 128);
    {
      const int o0 = (lane >> 4) << 5;           // 0,32,64,96
      i32x8 av[2], bv[4];
#pragma unroll
      for (int m = 0; m < 2; ++m) {
        int row = wr * 32 + m * 16 + (lane & 15);
        const unsigned char* base = &As[cur][0] + row * 128;
        int sw = (row & 7) << 4;
        *(uint4*)&av[m] = *(const uint4*)(base + (o0 ^ sw));
        *((uint4*)&av[m] + 1) = *(const uint4*)(base + ((o0 + 16) ^ sw));
      }
#pragma unroll
      for (int n = 0; n < 4; ++n) {
        int row = wc * 64 + n * 16 + (lane & 15);
        const unsigned char* base = &Bs[cur][0] + row * 128;
        int sw = (row & 7) << 4;
        *(uint4*)&bv[n] = *(const uint4*)(base + (o0 ^ sw));
        *((uint4*)&bv[n] + 1) = *(const uint4*)(base + ((o0 + 16) ^ sw));
      }
#pragma unroll
      for (int m = 0; m < 2; ++m)
#pragma unroll
        for (int n = 0; n < 4; ++n)
          acc[m][n] = __builtin_amdgcn_mfma_scale_f32_16x16x128_f8f6f4(
              av[m], bv[n], acc[m][n], 0, 0, 0, 0x7f7f7f7f, 0, 0x7f7f7f7f);
    }
    asm volatile("s_waitcnt vmcnt(0) lgkmcnt(0)" ::: "memory");
    __builtin_amdgcn_sched_barrier(0);
    __builtin_amdgcn_s_barrier();
    cur ^= 1;
  }
#undef STAGE_DC
  // C/D layout: col=lane&15, row=(lane>>4)*4+j  (shape-determined); bf16 store
#pragma unroll
  for (int m = 0; m < 2; ++m)
#pragma unroll
    for (int n = 0; n < 4; ++n) {
      int col = tn0 + wc * 64 + n * 16 + (lane & 15);
      int rb = tm0 + wr * 32 + m * 16 + ((lane >> 4) << 2);
#pragma unroll
      for (int j = 0; j < 4; ++j)
        C[(long)(rb + j) * ND + col] = f2bf(acc[m][n][j]);
    }
}

// ---------------- direct-conv bf16 MFMA GEMM: 32 pixels x 64 oc, K=9x64 -----------
template <int EPI>
__global__ __launch_bounds__(128) void gemm_conv(
    const unsigned short* __restrict__ A, const unsigned short* __restrict__ Bw,
    void* __restrict__ Cv, const float* __restrict__ bias,
    const unsigned short* __restrict__ zp, int batchBase) {
  __shared__ unsigned short As[2][32 * 64];
  __shared__ unsigned short Bs[2][64 * 64];
  const int tid = threadIdx.x;
  const int wave = tid >> 6, lane = tid & 63;
  const int tm0 = xcd_swz(blockIdx.x, gridDim.x) * 32;
  f32x4 acc[2][2] = {};
  int aRow[2], aColB[2], aDst[2], py[2], px[2];
  long pb[2];
#pragma unroll
  for (int t = 0; t < 2; ++t) {
    int o = t * 2048 + tid * 16;
    int row = o >> 7;
    aRow[t] = row;
    aColB[t] = (o & 127) ^ ((row & 7) << 4);
    aDst[t] = t * 2048 + wave * 1024;
    int m = tm0 + row;
    int bl = m / NPIX, r = m - bl * NPIX;
    py[t] = r / WW;
    px[t] = r - py[t] * WW;
    pb[t] = (long)bl * NPIX;
  }
  int bRow[4], bColE[4], bDst[4];
#pragma unroll
  for (int t = 0; t < 4; ++t) {
    int o = t * 2048 + tid * 16;
    int row = o >> 7;
    bRow[t] = row;
    bColE[t] = ((o & 127) ^ ((row & 7) << 4)) >> 1;
    bDst[t] = t * 2048 + wave * 1024;
  }
#define STAGE_CV(buf, uv)                                                              \
  do {                                                                                 \
    int u_ = (uv) / 3, v_ = (uv) - u_ * 3;                                             \
    _Pragma("unroll") for (int t = 0; t < 2; ++t) {                                    \
      int yy = py[t] + u_ - 1, xx = px[t] + v_ - 1;                                    \
      const unsigned short* src =                                                      \
          ((unsigned)yy < (unsigned)HH && (unsigned)xx < (unsigned)WW)                 \
              ? A + (pb[t] + yy * WW + xx) * CC + (aColB[t] >> 1)                      \
              : zp;                                                                    \
      __builtin_amdgcn_global_load_lds(                                                \
          (const __attribute__((address_space(1))) void*)src,                          \
          (__attribute__((address_space(3))) void*)((char*)&As[buf][0] + aDst[t]),     \
          16, 0, 0);                                                                   \
    }                                                                                  \
    _Pragma("unroll") for (int t = 0; t < 4; ++t)                                      \
        __builtin_amdgcn_global_load_lds(                                              \
            (const __attribute__((address_space(1))) void*)(Bw +                       \
                (long)bRow[t] * KC + (uv)*64 + bColE[t]),                              \
            (__attribute__((address_space(3))) void*)((char*)&Bs[buf][0] + bDst[t]),   \
            16, 0, 0);                                                                 \
  } while (0)

  STAGE_CV(0, 0);
  asm volatile("s_waitcnt vmcnt(0)");
  __builtin_amdgcn_s_barrier();
  int cur = 0;
  for (int uv = 0; uv < 9; ++uv) {
    if (uv + 1 < 9) STAGE_CV(cur ^ 1, uv + 1);
#pragma unroll
    for (int ks = 0; ks < 2; ++ks) {
      const int cbase = ks * 64 + ((lane >> 4) << 4);
      bf16x8 av[2], bv[2];
#pragma unroll
      for (int m = 0; m < 2; ++m) {
        int row = m * 16 + (lane & 15);
        av[m] = *(const bf16x8*)((const char*)&As[cur][0] + row * 128 + (cbase ^ ((row & 7) << 4)));
      }
#pragma unroll
      for (int n = 0; n < 2; ++n) {
        int row = wave * 32 + n * 16 + (lane & 15);
        bv[n] = *(const bf16x8*)((const char*)&Bs[cur][0] + row * 128 + (cbase ^ ((row & 7) << 4)));
      }
#pragma unroll
      for (int m = 0; m < 2; ++m)
#pragma unroll
        for (int n = 0; n < 2; ++n)
          acc[m][n] = __builtin_amdgcn_mfma_f32_16x16x32_bf16(av[m], bv[n], acc[m][n], 0, 0, 0);
    }
    asm volatile("s_waitcnt vmcnt(0) lgkmcnt(0)" ::: "memory");
    __builtin_amdgcn_sched_barrier(0);
    __builtin_amdgcn_s_barrier();
    cur ^= 1;
  }
#undef STAGE_CV
#pragma unroll
  for (int m = 0; m < 2; ++m)
#pragma unroll
    for (int n = 0; n < 2; ++n) {
      int col = wave * 32 + n * 16 + (lane & 15);
      float bb_ = bias[col];
      int rb = tm0 + m * 16 + ((lane >> 4) << 2);
      if (EPI == 1) {
#pragma unroll
        for (int j = 0; j < 4; ++j) {
          float v = eluf(acc[m][n][j] + bb_);
          ((unsigned short*)Cv)[(long)(rb + j) * CC + col] = f2bf(v);
        }
      } else {
        int bl = batchBase + rb / NPIX;
        int r = rb % NPIX;
        float4 o4 = make_float4(eluf(acc[m][n][0] + bb_), eluf(acc[m][n][1] + bb_),
                                eluf(acc[m][n][2] + bb_), eluf(acc[m][n][3] + bb_));
        *(float4*)((float*)Cv + ((long)(bl * CC + col)) * NPIX + r) = o4;
      }
    }
}

// ---------------- 9-tap diagonal patch box-sum + inv-norm ----------------
// All tap loads ALIGNED: dv=0 taps are 16B-aligned f32x4; dv=+-1 taps are covered
// by two aligned f32x4 (a-4/.w + a/.xyz, or a/.yzw + a+4/.x) with register
// renaming into the same adds -> identical values, identical order (bit-identical),
// but dwordx4 loads instead of 4x split dword (the f32x4u align-4 penalty).
__global__ __launch_bounds__(192) void patchsum_row(
    const float* __restrict__ G0, float* __restrict__ O0, long sBuf,
    const float* __restrict__ invn, int batchBase) {
  int swz = xcd_swz(blockIdx.x, gridDim.x);
  int z = swz / LQ, p = swz - z * LQ;
  const float* G = G0 + (long)z * sBuf;
  float* O = O0 + (long)z * sBuf;
  int i = p / WD, j = p - i * WD;
  int t = threadIdx.x;
  bool jm = (j > 0), jp = (j < WD - 1);
#pragma unroll
  for (int ps = 0; ps < 3; ++ps) {
    int q = 4 * (ps * 192 + t);
    int li = q / WD, lj = q - li * WD;
    float a0 = 0.f, a1 = 0.f, a2 = 0.f, a3 = 0.f;
#pragma unroll
    for (int du = -1; du <= 1; ++du) {
      if ((unsigned)(i + du) >= (unsigned)HD) continue;    // block-uniform
      if ((unsigned)(li + du) >= (unsigned)HD) continue;   // thread-level
      const float* a = G + (long)(p + du * WD) * LQ + (q + du * WD);  // aligned base
      if (jm) {                                            // dv = -1
        f32x4 A4 = *(const f32x4*)(a - LQ - 4);
        f32x4 B4 = *(const f32x4*)(a - LQ);
        if (lj > 0) a0 += A4.w;
        a1 += B4.x; a2 += B4.y; a3 += B4.z;
      }
      {                                                    // dv = 0
        f32x4 v = *(const f32x4*)a;
        a0 += v.x; a1 += v.y; a2 += v.z; a3 += v.w;
      }
      if (jp) {                                            // dv = +1
        f32x4 A4 = *(const f32x4*)(a + LQ);
        f32x4 B4 = *(const f32x4*)(a + LQ + 4);
        a0 += A4.y; a1 += A4.z; a2 += A4.w;
        if (lj < 44) a3 += B4.x;
      }
    }
    f32x4 n4 = *(const f32x4*)(invn + (long)(batchBase + z) * LQ + q);
    *(float4*)(O + (long)p * LQ + q) =
        make_float4(a0 * n4.x, a1 * n4.y, a2 * n4.z, a3 * n4.w);
  }
}

// ---------------- fused fuse_conv1+fuse_conv2 + masked softmax + argmax + fp8 ----
// Main-path taps use aligned-pair loads (same value/order as before, bit-identical).
__global__ __launch_bounds__(192) void fuse_softmax_row(
    const float* __restrict__ P0, long sBuf, const float* __restrict__ mmb,
    unsigned char* __restrict__ Ab, long sAb, float* __restrict__ offout, int batchBase) {
  int swz = xcd_swz(blockIdx.x, gridDim.x);
  int z = swz / LQ, p = swz - z * LQ;
  const float* P = P0 + (long)z * sBuf;
  int b = batchBase + z;
  int i = p / WD, j = p - i * WD;
  int t = threadIdx.x;
  int pp = j * HD + i;

  int rr[3];
  bool dok[3];
#pragma unroll
  for (int dd = 0; dd < 3; ++dd) {
    int a = pp + dd - 1;
    dok[dd] = ((unsigned)a < (unsigned)LQ);
    rr[dd] = dok[dd] ? (a % HD) * WD + (a / HD) : 0;
  }

  float zv[3][4], mv[3][4];
  float mx = -1e30f;
#pragma unroll
  for (int ps = 0; ps < 3; ++ps) {
    int q = 4 * (ps * 192 + t);
    int li = q / WD, lj = q - li * WD;
    float a0 = 0.f, a1 = 0.f, a2 = 0.f, a3 = 0.f;
#pragma unroll
    for (int dd = 0; dd < 3; ++dd) {
      if (!dok[dd]) continue;
      int r = rr[dd];
      bool rm = (r > 0), rp = (r < LQ - 1);
      const float* rowp = P + (long)r * LQ;
      int lid = li + dd - 1;
      if ((unsigned)lid < (unsigned)HD) {                  // main path (aligned)
        long cb = (long)lid * WD + lj;                     // cb % 4 == 0
        f32x4 v0 = *(const f32x4*)(rowp + cb);
        float vmx = 0.f, vmy = 0.f, vmz = 0.f, vmw = 0.f;
        float vpx = 0.f, vpy = 0.f, vpz = 0.f, vpw = 0.f;
        if (rm) {
          f32x4 m0 = *(const f32x4*)(rowp - LQ + cb - 4);
          f32x4 m1 = *(const f32x4*)(rowp - LQ + cb);
          vmx = m0.w; vmy = m1.x; vmz = m1.y; vmw = m1.z;
        }
        if (rp) {
          f32x4 p0 = *(const f32x4*)(rowp + LQ + cb);
          f32x4 p1 = *(const f32x4*)(rowp + LQ + cb + 4);
          vpx = p0.y; vpy = p0.z; vpz = p0.w; vpw = p1.x;
        }
        { float s = v0.x; if (rm && cb > 0) s += vmx; if (rp) s += vpx; a0 += s; }
        { float s = v0.y; if (rm) s += vmy; if (rp) s += vpy; a1 += s; }
        { float s = v0.z; if (rm) s += vmz; if (rp) s += vpz; a2 += s; }
        { float s = v0.w; if (rm) s += vmw; if (rp && cb < LQ - 4) s += vpw; a3 += s; }
      } else if (lid == -1) {                              // wrap-low (li==0, d=-1)
        long cb = (long)(HD - 1) * WD + lj - 1;
        f32x4u v0 = *(const f32x4u*)(rowp + cb);
        f32x4u vm = {0.f, 0.f, 0.f, 0.f}, vp = {0.f, 0.f, 0.f, 0.f};
        if (rm) vm = *(const f32x4u*)(rowp - LQ + cb - 1);
        if (rp) vp = *(const f32x4u*)(rowp + LQ + cb + 1);
        if (lj >= 1) { float s = v0.x; if (rm) s += vm.x; if (rp) s += vp.x; a0 += s; }
        { float s = v0.y; if (rm) s += vm.y; if (rp) s += vp.y; a1 += s; }
        { float s = v0.z; if (rm) s += vm.z; if (rp) s += vp.z; a2 += s; }
        { float s = v0.w; if (rm) s += vm.w; if (rp) s += vp.w; a3 += s; }
      } else {                                             // lid == HD (li==47, d=+1)
        long cb = (long)lj + 1;
        f32x4u v0 = *(const f32x4u*)(rowp + cb);
        f32x4u vm = {0.f, 0.f, 0.f, 0.f}, vp = {0.f, 0.f, 0.f, 0.f};
        if (rm) vm = *(const f32x4u*)(rowp - LQ + cb - 1);
        if (rp) vp = *(const f32x4u*)(rowp + LQ + cb + 1);
        { float s = v0.x; if (rm) s += vm.x; if (rp) s += vp.x; a0 += s; }
        { float s = v0.y; if (rm) s += vm.y; if (rp) s += vp.y; a1 += s; }
        { float s = v0.z; if (rm) s += vm.z; if (rp) s += vp.z; a2 += s; }
        if (lj < 44) { float s = v0.w; if (rm) s += vm.w; if (rp) s += vp.w; a3 += s; }
      }
    }
    f32x4 m4 = *(const f32x4*)(mmb + (long)b * LQ + q);
    mv[ps][0] = m4.x; mv[ps][1] = m4.y; mv[ps][2] = m4.z; mv[ps][3] = m4.w;
    zv[ps][0] = (m4.x != 0.f) ? a0 * 10.f : 0.f;
    zv[ps][1] = (m4.y != 0.f) ? a1 * 10.f : 0.f;
    zv[ps][2] = (m4.z != 0.f) ? a2 * 10.f : 0.f;
    zv[ps][3] = (m4.w != 0.f) ? a3 * 10.f : 0.f;
#pragma unroll
    for (int e = 0; e < 4; ++e) mx = fmaxf(mx, zv[ps][e]);
  }

  // 3-wave shuffle reductions
  __shared__ float s_m[3], s_s[3], s_av[3];
  __shared__ int s_ai[3];
  int wv = t >> 6;
#pragma unroll
  for (int off = 32; off; off >>= 1) mx = fmaxf(mx, __shfl_xor(mx, off));
  if ((t & 63) == 0) s_m[wv] = mx;
  __syncthreads();
  float M = fmaxf(s_m[0], fmaxf(s_m[1], s_m[2]));

  float sum = 0.f;
  float ev[3][4];
#pragma unroll
  for (int ps = 0; ps < 3; ++ps)
#pragma unroll
    for (int e = 0; e < 4; ++e) {
      ev[ps][e] = expf(zv[ps][e] - M);
      sum += ev[ps][e];
    }
#pragma unroll
  for (int off = 32; off; off >>= 1) sum += __shfl_xor(sum, off);
  if ((t & 63) == 0) s_s[wv] = sum;
  __syncthreads();
  float inv = 1.f / (s_s[0] + s_s[1] + s_s[2]);

  float bv = -1.f;
  int bi = 0;
  unsigned char* arow = Ab + (long)z * sAb + (long)p * LQ;
#pragma unroll
  for (int ps = 0; ps < 3; ++ps) {
    int q = 4 * (ps * 192 + t);
    float post0 = (mv[ps][0] != 0.f) ? ev[ps][0] * inv : 0.f;
    float post1 = (mv[ps][1] != 0.f) ? ev[ps][1] * inv : 0.f;
    float post2 = (mv[ps][2] != 0.f) ? ev[ps][2] * inv : 0.f;
    float post3 = (mv[ps][3] != 0.f) ? ev[ps][3] * inv : 0.f;
    if (post0 > bv) { bv = post0; bi = q; }
    if (post1 > bv) { bv = post1; bi = q + 1; }
    if (post2 > bv) { bv = post2; bi = q + 2; }
    if (post3 > bv) { bv = post3; bi = q + 3; }
    int pk = 0;
    pk = __builtin_amdgcn_cvt_pk_fp8_f32(post0, post1, pk, false);
    pk = __builtin_amdgcn_cvt_pk_fp8_f32(post2, post3, pk, true);
    *(unsigned*)(arow + q) = (unsigned)pk;       // q % 4 == 0 -> aligned
  }
#pragma unroll
  for (int off = 32; off; off >>= 1) {
    float ov = __shfl_xor(bv, off);
    int oi = __shfl_xor(bi, off);
    if (ov > bv || (ov == bv && oi < bi)) { bv = ov; bi = oi; }
  }
  if ((t & 63) == 0) { s_av[wv] = bv; s_ai[wv] = bi; }
  __syncthreads();
  if (t == 0) {
    float fbv = s_av[0];
    int fbi = s_ai[0];
    for (int k = 1; k < 3; ++k) {
      if (s_av[k] > fbv || (s_av[k] == fbv && s_ai[k] < fbi)) { fbv = s_av[k]; fbi = s_ai[k]; }
    }
    offout[((long)b * 2 + 0) * LQ + p] = (float)(fbi / WD - i);
    offout[((long)b * 2 + 1) * LQ + p] = (float)(fbi % WD - j);
  }
}

// ---------------- pack deconv weights WdT[(ku*4+kv)*64+o][l] as fp8 e4m3 -----------
__global__ void pack_wd(const float* __restrict__ bimg, unsigned char* __restrict__ WdT,
                        long sWd, int batchBase) {
  int z = blockIdx.z;
  int b = batchBase + z;
  int idx = blockIdx.x * 256 + threadIdx.x;      // < ND*LQ
  int n = idx / LQ, l = idx - n * LQ;
  int o = n % CC, kuv = n / CC, ku = kuv >> 2, kv = kuv & 3;
  int li = l / WD, lj = l % WD;
  int yy = 2 * li + ku - 1, xx = 2 * lj + kv - 1;
  float v = 0.f;
  if ((unsigned)yy < (unsigned)HH && (unsigned)xx < (unsigned)WW)
    v = bimg[((long)(b * CC + o) * HH + yy) * WW + xx];
  int pk = __builtin_amdgcn_cvt_pk_fp8_f32(v, 0.f, 0, false);
  WdT[(long)z * sWd + idx] = (unsigned char)(pk & 0xff);
}

// ---------------- scatter deconv GEMM result (bf16) into bf16 HWC y_pre ------------
__global__ void scatter_deconv(const unsigned short* __restrict__ Mo, long sMo,
                               unsigned short* __restrict__ ypre, int batchBase) {
  int z = blockIdx.z;
  int b = batchBase + z;
  int o = (threadIdx.x & 31) * 2, xq = threadIdx.x >> 5;
  int X = blockIdx.x * 8 + xq, Y = blockIdx.y;   // grid (12, 96, NB)
  const unsigned short* M = Mo + (long)z * sMo;
  int iA, kuA, iB, kuB;
  if (Y & 1) { iA = (Y + 1) >> 1; kuA = 0; iB = (Y - 1) >> 1; kuB = 2; }
  else       { iA = Y >> 1;       kuA = 1; iB = (Y >> 1) - 1; kuB = 3; }
  int jA, kvA, jB, kvB;
  if (X & 1) { jA = (X + 1) >> 1; kvA = 0; jB = (X - 1) >> 1; kvB = 2; }
  else       { jA = X >> 1;       kvA = 1; jB = (X >> 1) - 1; kvB = 3; }
  int is[2] = {iA, iB}, kus[2] = {kuA, kuB};
  int js[2] = {jA, jB}, kvs[2] = {kvA, kvB};
  float s0 = 0.f, s1 = 0.f;
#pragma unroll
  for (int a = 0; a < 2; ++a) {
    if ((unsigned)is[a] >= (unsigned)HD) continue;
#pragma unroll
    for (int c = 0; c < 2; ++c) {
      if ((unsigned)js[c] >= (unsigned)WD) continue;
      unsigned u = *(const unsigned*)(M + (long)(is[a] * WD + js[c]) * ND +
                                      (kus[a] * 4 + kvs[c]) * CC + o);
      s0 += bf2f((unsigned short)(u & 0xffffu));
      s1 += bf2f((unsigned short)(u >> 16));
    }
  }
  unsigned outw = (unsigned)f2bf(0.25f * s0) | ((unsigned)f2bf(0.25f * s1) << 16);
  *(unsigned*)(ypre + ((long)b * NPIX + Y * WW + X) * CC + o) = outw;
}

// ---------------- pack conv weights as bf16 [oc][(u*3+v)*64+c] ----------------
__global__ void pack_w(const float* __restrict__ w1, const float* __restrict__ w2,
                       unsigned short* __restrict__ w1t, unsigned short* __restrict__ w2t) {
  int idx = blockIdx.x * 256 + threadIdx.x;      // < 2*CC*KC
  int sel = idx / (CC * KC);
  int r = idx % (CC * KC);
  int oc = r / KC, k = r % KC;
  int uv = k / CC, c = k % CC;
  const float* src = sel ? w2 : w1;
  float v = src[(long)(oc * CC + c) * 9 + uv];
  (sel ? w2t : w1t)[r] = f2bf(v);
}

// ---------------- host ----------------
extern "C" void kernel_launch(void* const* d_in, const int* in_sizes, int n_in,
                              void* d_out, int out_size, void* d_ws, size_t ws_size,
                              hipStream_t stream) {
  const float* f = (const float*)d_in[0];
  const float* bimg = (const float*)d_in[1];
  const float* mask = (const float*)d_in[2];
  const float* w1 = (const float*)d_in[3];
  const float* b1 = (const float*)d_in[4];
  const float* w2 = (const float*)d_in[5];
  const float* b2 = (const float*)d_in[6];
  float* out = (float*)d_out;
  float* offout = out + 4L * CC * NPIX;          // off region (written as float)

  char* w = (char*)d_ws;
  float* fdt = (float*)w;  w += 4L * LQ * CC * 4;
  float* bdt = (float*)w;  w += 4L * LQ * CC * 4;
  float* sqb = (float*)w;  w += 4L * LQ * 4;
  float* invn = (float*)w; w += 4L * LQ * 4;
  float* mmb = (float*)w;  w += 4L * LQ * 4;
  unsigned short* zpage = (unsigned short*)w; w += 256;   // zero page for OOB staging
  unsigned short* w1t = (unsigned short*)w; w += (long)CC * KC * 4;  // region fp32-sized
  unsigned short* w2t = (unsigned short*)w; w += (long)CC * KC * 4;
  unsigned short* ypre = (unsigned short*)w; w += 4L * NPIX * CC * 4;  // region fp32-sized

  size_t fixed = (size_t)(w - (char*)d_ws);
  size_t szS_full = (size_t)4 * LL * 4;
  size_t szS_seq = (size_t)LL * 4;
  size_t szM_full = (size_t)4 * LQ * ND * 4;     // fp32-sized region, bf16 used
  size_t szM_seq = (size_t)LQ * ND * 4;
  // layout: [fixed][R3 (P)][RM][R2 (G / fp8 overlays / ybf1)][pad]
  size_t need_full = fixed + szM_full + 2 * szS_full + 1024;
  bool full = (ws_size >= need_full);

  size_t szS = full ? szS_full : szS_seq;
  size_t szM = full ? szM_full : szM_seq;
  float* R3 = (float*)w;                         // P
  unsigned short* RM = (unsigned short*)(w + szS);
  float* R2 = (float*)(w + szS + szM);
  unsigned char* Abf = (unsigned char*)R2;       // fp8 post (4*LL bytes)
  unsigned char* Wbf = Abf + (full ? 4L * LL : LL);
  unsigned short* ybf1 = (unsigned short*)R2;    // post-deconv overlay (Abf dead then)

  long sS = full ? LL : 0;
  long sMe = full ? (long)LQ * ND : 0;           // ushort elements
  long sWd = full ? (long)ND * LQ : 0;           // bytes (fp8)
  long sAb = full ? LL : 0;                      // bytes (fp8)
  long sFD = (long)LQ * CC;
  int NB = full ? 4 : 1;
  int nIter = full ? 1 : 4;

  hipMemsetAsync(zpage, 0, 256, stream);
  pack_w<<<dim3(288), 256, 0, stream>>>(w1, w2, w1t, w2t);

  for (int itb = 0; itb < nIter; ++itb) {
    int bb = full ? 0 : itb;
    int Mtot = NB * NPIX;
    pack_fdbd<<<dim3(576, 1, NB), 256, 0, stream>>>(f, bimg, fdt, bdt, bb);
    sq_kernel<<<dim3(LQ, 1, NB), 64, 0, stream>>>(bdt, sqb, bb);
    prep_l<<<dim3(9, 1, NB), 256, 0, stream>>>(sqb, mask, invn, mmb, bb);
    // Gram matrix G = fdt * bdt^T  (K = 64, fp32, single-stage — argmax-sensitive)
    gram_gemm<<<dim3(LQ / 128, LQ / 128, NB), 256, 0, stream>>>(
        fdt + (long)bb * sFD, bdt + (long)bb * sFD, R2, sFD, sFD, sS);
    // 9-tap diagonal box-sum + inv-norm  (G in R2 -> P in R3), XCD-swizzled grid
    patchsum_row<<<dim3(LQ * NB), 192, 0, stream>>>(R2, R3, sS, invn, bb);
    // fused double fuse_conv + masked softmax + argmax + fp8 store (P -> Abf)
    fuse_softmax_row<<<dim3(LQ * NB), 192, 0, stream>>>(R3, sS, mmb, Abf, sAb, offout, bb);
    // deconv as MX-fp8 MFMA GEMM (64x128, BK=128, unit-scale K=128 instruction)
    pack_wd<<<dim3(9216, 1, NB), 256, 0, stream>>>(bimg, Wbf, sWd, bb);
    gemm_deconv<<<dim3(8 * (LQ / 64) * NB), 256, 0, stream>>>(
        Abf, Wbf, RM, LQ, sAb, sWd, sMe, LQ / 64);
    scatter_deconv<<<dim3(12, 96, NB), 256, 0, stream>>>(RM, sMe, ypre, bb);
    // conv1 -> conv2 as direct-conv bf16 MFMA GEMMs (32x64 tiles; bias+ELU fused)
    const unsigned short* src1 = ypre + (full ? 0 : (long)bb * NPIX * CC);
    gemm_conv<1><<<dim3(Mtot / 32), 128, 0, stream>>>(src1, w1t, ybf1, b1, zpage, bb);
    gemm_conv<2><<<dim3(Mtot / 32), 128, 0, stream>>>(ybf1, w2t, out, b2, zpage, bb);
  }
}

// Round 16
// 237.198 us; speedup vs baseline: 1.0575x; 1.0575x over previous
//
#include <hip/hip_runtime.h>
#include <math.h>

// ---------------- problem constants ----------------
constexpr int HD = 48, WD = 48, LQ = HD * WD;     // 2304 downsampled positions / patches
constexpr int CC = 64;                             // channels
constexpr int HH = 96, WW = 96, NPIX = HH * WW;    // 9216 full-res pixels
constexpr int KC = CC * 9;                         // 576 im2col K
constexpr int ND = 16 * CC;                        // 1024 deconv GEMM N
constexpr long LL = (long)LQ * LQ;                 // 5,308,416

typedef __attribute__((ext_vector_type(8))) short bf16x8;
typedef __attribute__((ext_vector_type(4))) float f32x4;
typedef __attribute__((ext_vector_type(8))) int i32x8;
// 4-byte-aligned float4 for unaligned-base tap loads (gfx9 dwordx4 needs only 4B align)
typedef float f32x4u __attribute__((ext_vector_type(4), aligned(4)));

static __device__ __forceinline__ float eluf(float x) {
  return x > 0.f ? x : expm1f(x);
}
static __device__ __forceinline__ unsigned short f2bf(float x) {
  unsigned u = __float_as_uint(x);
  unsigned r = (u + 0x7fffu + ((u >> 16) & 1u)) >> 16;
  return (unsigned short)r;
}
static __device__ __forceinline__ float bf2f(unsigned short h) {
  return __uint_as_float((unsigned)h << 16);
}
// bijective XCD swizzle (m204): consecutive outputs land on one XCD
static __device__ __forceinline__ int xcd_swz(int bid, int nwg) {
  int q = nwg >> 3, r8 = nwg & 7;
  int xcd = bid & 7, idx = bid >> 3;
  return (xcd < r8 ? xcd * (q + 1) : r8 * (q + 1) + (xcd - r8) * q) + idx;
}

// ---------------- pack downsampled f/b as [q][c] ----------------
__global__ void pack_fdbd(const float* __restrict__ f, const float* __restrict__ bimg,
                          float* __restrict__ fdt, float* __restrict__ bdt, int batchBase) {
  int b = batchBase + blockIdx.z;
  int idx = blockIdx.x * 256 + threadIdx.x;      // < CC*LQ = 147456
  int c = idx / LQ, r = idx % LQ;
  int y = r / WD, x = r % WD;
  long src = ((long)(b * CC + c) * HH + 2 * y) * WW + 2 * x;
  long dst = (long)b * LQ * CC + (long)r * CC + c;
  fdt[dst] = f[src];
  bdt[dst] = bimg[src];
}

// ---------------- per-position squared-channel sums ----------------
__global__ void sq_kernel(const float* __restrict__ bdt, float* __restrict__ sq, int batchBase) {
  int b = batchBase + blockIdx.z;
  int q = blockIdx.x;
  int c = threadIdx.x;                            // 64 = one wave
  float v = bdt[(long)b * LQ * CC + (long)q * CC + c];
  v *= v;
  for (int off = 32; off; off >>= 1) v += __shfl_down(v, off);
  if (c == 0) sq[b * LQ + q] = v;
}

// ---------------- inv patch norms + valid-mask mm ----------------
__global__ void prep_l(const float* __restrict__ sq, const float* __restrict__ mask,
                       float* __restrict__ invn, float* __restrict__ mmb, int batchBase) {
  int b = batchBase + blockIdx.z;
  int l = blockIdx.x * 256 + threadIdx.x;        // < LQ exactly (grid 9)
  int li = l / WD, lj = l % WD;
  float ss = 0.f, mv = 0.f;
  for (int du = -1; du <= 1; ++du)
    for (int dv = -1; dv <= 1; ++dv) {
      int yy = li + du, xx = lj + dv;
      if ((unsigned)yy < (unsigned)HD && (unsigned)xx < (unsigned)WD) {
        ss += sq[b * LQ + yy * WD + xx];
        mv += mask[b * LQ + yy * WD + xx];
      }
    }
  invn[b * LQ + l] = 1.f / fmaxf(sqrtf(ss), 1e-4f);
  mmb[b * LQ + l] = (mv == 0.f) ? 1.f : 0.f;
}

// ---------------- fp32 Gram GEMM: G = fdt * bdt^T, K=64 single-stage ---------------
__global__ __launch_bounds__(256) void gram_gemm(
    const float* __restrict__ A, const float* __restrict__ B, float* __restrict__ C,
    long sA, long sB, long sC) {
  constexpr int BM = 128, BN = 128, TM = 8, BK = 64;
  __shared__ float As[BK][BM];
  __shared__ float Bs[BK][BN];
  const int z = blockIdx.z;
  A += (long)z * sA;
  B += (long)z * sB;
  C += (long)z * sC;
  const int tn0 = blockIdx.x * BN;
  const int tm0 = blockIdx.y * BM;
  const int tid = threadIdx.x;
  const int tx = tid & 15, ty = tid >> 4;
#pragma unroll
  for (int s = 0; s < 8; ++s) {
    int idx = tid + s * 256;
    int row = idx & 127;
    int k4 = idx >> 7;
    float4 v = *(const float4*)(A + (long)(tm0 + row) * CC + k4 * 4);
    As[k4 * 4 + 0][row] = v.x;
    As[k4 * 4 + 1][row] = v.y;
    As[k4 * 4 + 2][row] = v.z;
    As[k4 * 4 + 3][row] = v.w;
    float4 u = *(const float4*)(B + (long)(tn0 + row) * CC + k4 * 4);
    Bs[k4 * 4 + 0][row] = u.x;
    Bs[k4 * 4 + 1][row] = u.y;
    Bs[k4 * 4 + 2][row] = u.z;
    Bs[k4 * 4 + 3][row] = u.w;
  }
  __syncthreads();
  float acc[TM][8];
#pragma unroll
  for (int m = 0; m < TM; ++m)
#pragma unroll
    for (int n = 0; n < 8; ++n) acc[m][n] = 0.f;
#pragma unroll 4
  for (int kk = 0; kk < BK; ++kk) {
    float a[TM], b[8];
    *(float4*)&a[0] = *(const float4*)&As[kk][ty * TM];
    *(float4*)&a[4] = *(const float4*)&As[kk][ty * TM + 4];
    *(float4*)&b[0] = *(const float4*)&Bs[kk][tx * 4];        // 16 lanes x 16B stride
    *(float4*)&b[4] = *(const float4*)&Bs[kk][64 + tx * 4];   // -> conflict-free
#pragma unroll
    for (int m = 0; m < TM; ++m)
#pragma unroll
      for (int n = 0; n < 8; ++n) acc[m][n] = fmaf(a[m], b[n], acc[m][n]);
  }
#pragma unroll
  for (int m = 0; m < TM; ++m) {
    long row = tm0 + ty * TM + m;
    *(float4*)(C + row * LQ + tn0 + tx * 4) =
        make_float4(acc[m][0], acc[m][1], acc[m][2], acc[m][3]);
    *(float4*)(C + row * LQ + tn0 + 64 + tx * 4) =
        make_float4(acc[m][4], acc[m][5], acc[m][6], acc[m][7]);
  }
}

// ---------------- deconv MX-fp8 MFMA GEMM, 64x128 tile, BK=128, 2-phase dbuf -------
__global__ __launch_bounds__(256) void gemm_deconv(
    const unsigned char* __restrict__ A, const unsigned char* __restrict__ B,
    unsigned short* __restrict__ C, int K, long sA, long sB, long sC, int tilesY) {
  int swz = xcd_swz(blockIdx.x, gridDim.x);
  int perz = tilesY * 8;
  int z = swz / perz, t2 = swz - z * perz;
  int ty = t2 >> 3, tx = t2 & 7;
  A += (long)z * sA;
  B += (long)z * sB;
  C += (long)z * sC;
  const int tid = threadIdx.x;
  const int wave = tid >> 6, lane = tid & 63;
  const int wr = wave >> 1, wc = wave & 1;
  const int tm0 = ty * 64, tn0 = tx * 128;
  __shared__ unsigned char As[2][64 * 128];      // 8KB/buf
  __shared__ unsigned char Bs[2][128 * 128];     // 16KB/buf
  f32x4 acc[2][4] = {};

  int aRow[2], aCol[2], aDst[2];
#pragma unroll
  for (int t = 0; t < 2; ++t) {
    int o = t * 4096 + tid * 16;
    int row = o >> 7;
    aRow[t] = row;
    aCol[t] = (o & 127) ^ ((row & 7) << 4);      // byte == element offset
    aDst[t] = t * 4096 + wave * 1024;            // byte, wave-uniform
  }
  int bRow[4], bCol[4], bDst[4];
#pragma unroll
  for (int t = 0; t < 4; ++t) {
    int o = t * 4096 + tid * 16;
    int row = o >> 7;
    bRow[t] = row;
    bCol[t] = (o & 127) ^ ((row & 7) << 4);
    bDst[t] = t * 4096 + wave * 1024;
  }

#define STAGE_DC(buf, k0)                                                             \
  do {                                                                                \
    _Pragma("unroll") for (int t = 0; t < 2; ++t)                                     \
        __builtin_amdgcn_global_load_lds(                                             \
            (const __attribute__((address_space(1))) void*)(A +                       \
                (long)(tm0 + aRow[t]) * K + (k0) + aCol[t]),                          \
            (__attribute__((address_space(3))) void*)((char*)&As[buf][0] + aDst[t]),  \
            16, 0, 0);                                                                \
    _Pragma("unroll") for (int t = 0; t < 4; ++t)                                     \
        __builtin_amdgcn_global_load_lds(                                             \
            (const __attribute__((address_space(1))) void*)(B +                       \
                (long)(tn0 + bRow[t]) * K + (k0) + bCol[t]),                          \
            (__attribute__((address_space(3))) void*)((char*)&Bs[buf][0] + bDst[t]),  \
            16, 0, 0);                                                                \
  } while (0)

  STAGE_DC(0, 0);
  asm volatile("s_waitcnt vmcnt(0)");
  __builtin_amdgcn_s_barrier();
  int cur = 0;
  for (int k0 = 0; k0 < K; k0 += 128) {          // 18 steps
    if (k0 + 128 < K) STAGE_DC(cur ^ 1, k0 + 128);
    {
      const int o0 = (lane >> 4) << 5;           // 0,32,64,96
      i32x8 av[2], bv[4];
#pragma unroll
      for (int m = 0; m < 2; ++m) {
        int row = wr * 32 + m * 16 + (lane & 15);
        const unsigned char* base = &As[cur][0] + row * 128;
        int sw = (row & 7) << 4;
        *(uint4*)&av[m] = *(const uint4*)(base + (o0 ^ sw));
        *((uint4*)&av[m] + 1) = *(const uint4*)(base + ((o0 + 16) ^ sw));
      }
#pragma unroll
      for (int n = 0; n < 4; ++n) {
        int row = wc * 64 + n * 16 + (lane & 15);
        const unsigned char* base = &Bs[cur][0] + row * 128;
        int sw = (row & 7) << 4;
        *(uint4*)&bv[n] = *(const uint4*)(base + (o0 ^ sw));
        *((uint4*)&bv[n] + 1) = *(const uint4*)(base + ((o0 + 16) ^ sw));
      }
#pragma unroll
      for (int m = 0; m < 2; ++m)
#pragma unroll
        for (int n = 0; n < 4; ++n)
          acc[m][n] = __builtin_amdgcn_mfma_scale_f32_16x16x128_f8f6f4(
              av[m], bv[n], acc[m][n], 0, 0, 0, 0x7f7f7f7f, 0, 0x7f7f7f7f);
    }
    asm volatile("s_waitcnt vmcnt(0) lgkmcnt(0)" ::: "memory");
    __builtin_amdgcn_sched_barrier(0);
    __builtin_amdgcn_s_barrier();
    cur ^= 1;
  }
#undef STAGE_DC
  // C/D layout: col=lane&15, row=(lane>>4)*4+j  (shape-determined); bf16 store
#pragma unroll
  for (int m = 0; m < 2; ++m)
#pragma unroll
    for (int n = 0; n < 4; ++n) {
      int col = tn0 + wc * 64 + n * 16 + (lane & 15);
      int rb = tm0 + wr * 32 + m * 16 + ((lane >> 4) << 2);
#pragma unroll
      for (int j = 0; j < 4; ++j)
        C[(long)(rb + j) * ND + col] = f2bf(acc[m][n][j]);
    }
}

// ---------------- direct-conv bf16 MFMA GEMM: 32 pixels x 64 oc, K=9x64 -----------
template <int EPI>
__global__ __launch_bounds__(128) void gemm_conv(
    const unsigned short* __restrict__ A, const unsigned short* __restrict__ Bw,
    void* __restrict__ Cv, const float* __restrict__ bias,
    const unsigned short* __restrict__ zp, int batchBase) {
  __shared__ unsigned short As[2][32 * 64];
  __shared__ unsigned short Bs[2][64 * 64];
  const int tid = threadIdx.x;
  const int wave = tid >> 6, lane = tid & 63;
  const int tm0 = xcd_swz(blockIdx.x, gridDim.x) * 32;
  f32x4 acc[2][2] = {};
  int aRow[2], aColB[2], aDst[2], py[2], px[2];
  long pb[2];
#pragma unroll
  for (int t = 0; t < 2; ++t) {
    int o = t * 2048 + tid * 16;
    int row = o >> 7;
    aRow[t] = row;
    aColB[t] = (o & 127) ^ ((row & 7) << 4);
    aDst[t] = t * 2048 + wave * 1024;
    int m = tm0 + row;
    int bl = m / NPIX, r = m - bl * NPIX;
    py[t] = r / WW;
    px[t] = r - py[t] * WW;
    pb[t] = (long)bl * NPIX;
  }
  int bRow[4], bColE[4], bDst[4];
#pragma unroll
  for (int t = 0; t < 4; ++t) {
    int o = t * 2048 + tid * 16;
    int row = o >> 7;
    bRow[t] = row;
    bColE[t] = ((o & 127) ^ ((row & 7) << 4)) >> 1;
    bDst[t] = t * 2048 + wave * 1024;
  }
#define STAGE_CV(buf, uv)                                                              \
  do {                                                                                 \
    int u_ = (uv) / 3, v_ = (uv) - u_ * 3;                                             \
    _Pragma("unroll") for (int t = 0; t < 2; ++t) {                                    \
      int yy = py[t] + u_ - 1, xx = px[t] + v_ - 1;                                    \
      const unsigned short* src =                                                      \
          ((unsigned)yy < (unsigned)HH && (unsigned)xx < (unsigned)WW)                 \
              ? A + (pb[t] + yy * WW + xx) * CC + (aColB[t] >> 1)                      \
              : zp;                                                                    \
      __builtin_amdgcn_global_load_lds(                                                \
          (const __attribute__((address_space(1))) void*)src,                          \
          (__attribute__((address_space(3))) void*)((char*)&As[buf][0] + aDst[t]),     \
          16, 0, 0);                                                                   \
    }                                                                                  \
    _Pragma("unroll") for (int t = 0; t < 4; ++t)                                      \
        __builtin_amdgcn_global_load_lds(                                              \
            (const __attribute__((address_space(1))) void*)(Bw +                       \
                (long)bRow[t] * KC + (uv)*64 + bColE[t]),                              \
            (__attribute__((address_space(3))) void*)((char*)&Bs[buf][0] + bDst[t]),   \
            16, 0, 0);                                                                 \
  } while (0)

  STAGE_CV(0, 0);
  asm volatile("s_waitcnt vmcnt(0)");
  __builtin_amdgcn_s_barrier();
  int cur = 0;
  for (int uv = 0; uv < 9; ++uv) {
    if (uv + 1 < 9) STAGE_CV(cur ^ 1, uv + 1);
#pragma unroll
    for (int ks = 0; ks < 2; ++ks) {
      const int cbase = ks * 64 + ((lane >> 4) << 4);
      bf16x8 av[2], bv[2];
#pragma unroll
      for (int m = 0; m < 2; ++m) {
        int row = m * 16 + (lane & 15);
        av[m] = *(const bf16x8*)((const char*)&As[cur][0] + row * 128 + (cbase ^ ((row & 7) << 4)));
      }
#pragma unroll
      for (int n = 0; n < 2; ++n) {
        int row = wave * 32 + n * 16 + (lane & 15);
        bv[n] = *(const bf16x8*)((const char*)&Bs[cur][0] + row * 128 + (cbase ^ ((row & 7) << 4)));
      }
#pragma unroll
      for (int m = 0; m < 2; ++m)
#pragma unroll
        for (int n = 0; n < 2; ++n)
          acc[m][n] = __builtin_amdgcn_mfma_f32_16x16x32_bf16(av[m], bv[n], acc[m][n], 0, 0, 0);
    }
    asm volatile("s_waitcnt vmcnt(0) lgkmcnt(0)" ::: "memory");
    __builtin_amdgcn_sched_barrier(0);
    __builtin_amdgcn_s_barrier();
    cur ^= 1;
  }
#undef STAGE_CV
#pragma unroll
  for (int m = 0; m < 2; ++m)
#pragma unroll
    for (int n = 0; n < 2; ++n) {
      int col = wave * 32 + n * 16 + (lane & 15);
      float bb_ = bias[col];
      int rb = tm0 + m * 16 + ((lane >> 4) << 2);
      if (EPI == 1) {
#pragma unroll
        for (int j = 0; j < 4; ++j) {
          float v = eluf(acc[m][n][j] + bb_);
          ((unsigned short*)Cv)[(long)(rb + j) * CC + col] = f2bf(v);
        }
      } else {
        int bl = batchBase + rb / NPIX;
        int r = rb % NPIX;
        float4 o4 = make_float4(eluf(acc[m][n][0] + bb_), eluf(acc[m][n][1] + bb_),
                                eluf(acc[m][n][2] + bb_), eluf(acc[m][n][3] + bb_));
        *(float4*)((float*)Cv + ((long)(bl * CC + col)) * NPIX + r) = o4;
      }
    }
}

// ---------------- 9-tap diagonal patch box-sum + inv-norm (lane-contiguous f4) ----
__global__ __launch_bounds__(192) void patchsum_row(
    const float* __restrict__ G0, float* __restrict__ O0, long sBuf,
    const float* __restrict__ invn, int batchBase) {
  int swz = xcd_swz(blockIdx.x, gridDim.x);
  int z = swz / LQ, p = swz - z * LQ;
  const float* G = G0 + (long)z * sBuf;
  float* O = O0 + (long)z * sBuf;
  int i = p / WD, j = p - i * WD;
  int t = threadIdx.x;
#pragma unroll
  for (int ps = 0; ps < 3; ++ps) {
    int q = 4 * (ps * 192 + t);
    int li = q / WD, lj = q - li * WD;
    float a0 = 0.f, a1 = 0.f, a2 = 0.f, a3 = 0.f;
#pragma unroll
    for (int du = -1; du <= 1; ++du) {
      if ((unsigned)(i + du) >= (unsigned)HD) continue;    // block-uniform
      if ((unsigned)(li + du) >= (unsigned)HD) continue;   // thread-level
#pragma unroll
      for (int dv = -1; dv <= 1; ++dv) {
        if ((unsigned)(j + dv) >= (unsigned)WD) continue;  // block-uniform
        int D = du * WD + dv;
        f32x4u v = *(const f32x4u*)(G + (long)(p + D) * LQ + (q + D));
        if (dv < 0) {
          if (lj > 0) a0 += v.x;
          a1 += v.y; a2 += v.z; a3 += v.w;
        } else if (dv > 0) {
          a0 += v.x; a1 += v.y; a2 += v.z;
          if (lj < 44) a3 += v.w;
        } else {
          a0 += v.x; a1 += v.y; a2 += v.z; a3 += v.w;
        }
      }
    }
    f32x4 n4 = *(const f32x4*)(invn + (long)(batchBase + z) * LQ + q);
    *(float4*)(O + (long)p * LQ + q) =
        make_float4(a0 * n4.x, a1 * n4.y, a2 * n4.z, a3 * n4.w);
  }
}

// ---------------- fused fuse_conv1+fuse_conv2 + masked softmax + argmax + fp8 ----
__global__ __launch_bounds__(192) void fuse_softmax_row(
    const float* __restrict__ P0, long sBuf, const float* __restrict__ mmb,
    unsigned char* __restrict__ Ab, long sAb, float* __restrict__ offout, int batchBase) {
  int swz = xcd_swz(blockIdx.x, gridDim.x);
  int z = swz / LQ, p = swz - z * LQ;
  const float* P = P0 + (long)z * sBuf;
  int b = batchBase + z;
  int i = p / WD, j = p - i * WD;
  int t = threadIdx.x;
  int pp = j * HD + i;

  int rr[3];
  bool dok[3];
#pragma unroll
  for (int dd = 0; dd < 3; ++dd) {
    int a = pp + dd - 1;
    dok[dd] = ((unsigned)a < (unsigned)LQ);
    rr[dd] = dok[dd] ? (a % HD) * WD + (a / HD) : 0;
  }

  float zv[3][4], mv[3][4];
  float mx = -1e30f;
#pragma unroll
  for (int ps = 0; ps < 3; ++ps) {
    int q = 4 * (ps * 192 + t);
    int li = q / WD, lj = q - li * WD;
    float a0 = 0.f, a1 = 0.f, a2 = 0.f, a3 = 0.f;
#pragma unroll
    for (int dd = 0; dd < 3; ++dd) {
      if (!dok[dd]) continue;
      int r = rr[dd];
      bool rm = (r > 0), rp = (r < LQ - 1);
      const float* rowp = P + (long)r * LQ;
      int lid = li + dd - 1;
      if ((unsigned)lid < (unsigned)HD) {                  // main path
        long cb = (long)lid * WD + lj;
        f32x4u v0 = *(const f32x4u*)(rowp + cb);
        f32x4u vm = {0.f, 0.f, 0.f, 0.f}, vp = {0.f, 0.f, 0.f, 0.f};
        if (rm) vm = *(const f32x4u*)(rowp - LQ + cb - 1);
        if (rp) vp = *(const f32x4u*)(rowp + LQ + cb + 1);
        { float s = v0.x; if (rm && cb > 0) s += vm.x; if (rp) s += vp.x; a0 += s; }
        { float s = v0.y; if (rm) s += vm.y; if (rp) s += vp.y; a1 += s; }
        { float s = v0.z; if (rm) s += vm.z; if (rp) s += vp.z; a2 += s; }
        { float s = v0.w; if (rm) s += vm.w; if (rp && cb < LQ - 4) s += vp.w; a3 += s; }
      } else if (lid == -1) {                              // wrap-low (li==0, d=-1)
        long cb = (long)(HD - 1) * WD + lj - 1;
        f32x4u v0 = *(const f32x4u*)(rowp + cb);
        f32x4u vm = {0.f, 0.f, 0.f, 0.f}, vp = {0.f, 0.f, 0.f, 0.f};
        if (rm) vm = *(const f32x4u*)(rowp - LQ + cb - 1);
        if (rp) vp = *(const f32x4u*)(rowp + LQ + cb + 1);
        if (lj >= 1) { float s = v0.x; if (rm) s += vm.x; if (rp) s += vp.x; a0 += s; }
        { float s = v0.y; if (rm) s += vm.y; if (rp) s += vp.y; a1 += s; }
        { float s = v0.z; if (rm) s += vm.z; if (rp) s += vp.z; a2 += s; }
        { float s = v0.w; if (rm) s += vm.w; if (rp) s += vp.w; a3 += s; }
      } else {                                             // lid == HD (li==47, d=+1)
        long cb = (long)lj + 1;
        f32x4u v0 = *(const f32x4u*)(rowp + cb);
        f32x4u vm = {0.f, 0.f, 0.f, 0.f}, vp = {0.f, 0.f, 0.f, 0.f};
        if (rm) vm = *(const f32x4u*)(rowp - LQ + cb - 1);
        if (rp) vp = *(const f32x4u*)(rowp + LQ + cb + 1);
        { float s = v0.x; if (rm) s += vm.x; if (rp) s += vp.x; a0 += s; }
        { float s = v0.y; if (rm) s += vm.y; if (rp) s += vp.y; a1 += s; }
        { float s = v0.z; if (rm) s += vm.z; if (rp) s += vp.z; a2 += s; }
        if (lj < 44) { float s = v0.w; if (rm) s += vm.w; if (rp) s += vp.w; a3 += s; }
      }
    }
    f32x4 m4 = *(const f32x4*)(mmb + (long)b * LQ + q);
    mv[ps][0] = m4.x; mv[ps][1] = m4.y; mv[ps][2] = m4.z; mv[ps][3] = m4.w;
    zv[ps][0] = (m4.x != 0.f) ? a0 * 10.f : 0.f;
    zv[ps][1] = (m4.y != 0.f) ? a1 * 10.f : 0.f;
    zv[ps][2] = (m4.z != 0.f) ? a2 * 10.f : 0.f;
    zv[ps][3] = (m4.w != 0.f) ? a3 * 10.f : 0.f;
#pragma unroll
    for (int e = 0; e < 4; ++e) mx = fmaxf(mx, zv[ps][e]);
  }

  // 3-wave shuffle reductions
  __shared__ float s_m[3], s_s[3], s_av[3];
  __shared__ int s_ai[3];
  int wv = t >> 6;
#pragma unroll
  for (int off = 32; off; off >>= 1) mx = fmaxf(mx, __shfl_xor(mx, off));
  if ((t & 63) == 0) s_m[wv] = mx;
  __syncthreads();
  float M = fmaxf(s_m[0], fmaxf(s_m[1], s_m[2]));

  float sum = 0.f;
  float ev[3][4];
#pragma unroll
  for (int ps = 0; ps < 3; ++ps)
#pragma unroll
    for (int e = 0; e < 4; ++e) {
      ev[ps][e] = expf(zv[ps][e] - M);
      sum += ev[ps][e];
    }
#pragma unroll
  for (int off = 32; off; off >>= 1) sum += __shfl_xor(sum, off);
  if ((t & 63) == 0) s_s[wv] = sum;
  __syncthreads();
  float inv = 1.f / (s_s[0] + s_s[1] + s_s[2]);

  float bv = -1.f;
  int bi = 0;
  unsigned char* arow = Ab + (long)z * sAb + (long)p * LQ;
#pragma unroll
  for (int ps = 0; ps < 3; ++ps) {
    int q = 4 * (ps * 192 + t);
    float post0 = (mv[ps][0] != 0.f) ? ev[ps][0] * inv : 0.f;
    float post1 = (mv[ps][1] != 0.f) ? ev[ps][1] * inv : 0.f;
    float post2 = (mv[ps][2] != 0.f) ? ev[ps][2] * inv : 0.f;
    float post3 = (mv[ps][3] != 0.f) ? ev[ps][3] * inv : 0.f;
    if (post0 > bv) { bv = post0; bi = q; }
    if (post1 > bv) { bv = post1; bi = q + 1; }
    if (post2 > bv) { bv = post2; bi = q + 2; }
    if (post3 > bv) { bv = post3; bi = q + 3; }
    int pk = 0;
    pk = __builtin_amdgcn_cvt_pk_fp8_f32(post0, post1, pk, false);
    pk = __builtin_amdgcn_cvt_pk_fp8_f32(post2, post3, pk, true);
    *(unsigned*)(arow + q) = (unsigned)pk;       // q % 4 == 0 -> aligned
  }
#pragma unroll
  for (int off = 32; off; off >>= 1) {
    float ov = __shfl_xor(bv, off);
    int oi = __shfl_xor(bi, off);
    if (ov > bv || (ov == bv && oi < bi)) { bv = ov; bi = oi; }
  }
  if ((t & 63) == 0) { s_av[wv] = bv; s_ai[wv] = bi; }
  __syncthreads();
  if (t == 0) {
    float fbv = s_av[0];
    int fbi = s_ai[0];
    for (int k = 1; k < 3; ++k) {
      if (s_av[k] > fbv || (s_av[k] == fbv && s_ai[k] < fbi)) { fbv = s_av[k]; fbi = s_ai[k]; }
    }
    offout[((long)b * 2 + 0) * LQ + p] = (float)(fbi / WD - i);
    offout[((long)b * 2 + 1) * LQ + p] = (float)(fbi % WD - j);
  }
}

// ---------------- pack deconv weights WdT[(ku*4+kv)*64+o][l] as fp8 e4m3 -----------
__global__ void pack_wd(const float* __restrict__ bimg, unsigned char* __restrict__ WdT,
                        long sWd, int batchBase) {
  int z = blockIdx.z;
  int b = batchBase + z;
  int idx = blockIdx.x * 256 + threadIdx.x;      // < ND*LQ
  int n = idx / LQ, l = idx - n * LQ;
  int o = n % CC, kuv = n / CC, ku = kuv >> 2, kv = kuv & 3;
  int li = l / WD, lj = l % WD;
  int yy = 2 * li + ku - 1, xx = 2 * lj + kv - 1;
  float v = 0.f;
  if ((unsigned)yy < (unsigned)HH && (unsigned)xx < (unsigned)WW)
    v = bimg[((long)(b * CC + o) * HH + yy) * WW + xx];
  int pk = __builtin_amdgcn_cvt_pk_fp8_f32(v, 0.f, 0, false);
  WdT[(long)z * sWd + idx] = (unsigned char)(pk & 0xff);
}

// ---------------- scatter deconv GEMM result (bf16) into bf16 HWC y_pre ------------
__global__ void scatter_deconv(const unsigned short* __restrict__ Mo, long sMo,
                               unsigned short* __restrict__ ypre, int batchBase) {
  int z = blockIdx.z;
  int b = batchBase + z;
  int o = (threadIdx.x & 31) * 2, xq = threadIdx.x >> 5;
  int X = blockIdx.x * 8 + xq, Y = blockIdx.y;   // grid (12, 96, NB)
  const unsigned short* M = Mo + (long)z * sMo;
  int iA, kuA, iB, kuB;
  if (Y & 1) { iA = (Y + 1) >> 1; kuA = 0; iB = (Y - 1) >> 1; kuB = 2; }
  else       { iA = Y >> 1;       kuA = 1; iB = (Y >> 1) - 1; kuB = 3; }
  int jA, kvA, jB, kvB;
  if (X & 1) { jA = (X + 1) >> 1; kvA = 0; jB = (X - 1) >> 1; kvB = 2; }
  else       { jA = X >> 1;       kvA = 1; jB = (X >> 1) - 1; kvB = 3; }
  int is[2] = {iA, iB}, kus[2] = {kuA, kuB};
  int js[2] = {jA, jB}, kvs[2] = {kvA, kvB};
  float s0 = 0.f, s1 = 0.f;
#pragma unroll
  for (int a = 0; a < 2; ++a) {
    if ((unsigned)is[a] >= (unsigned)HD) continue;
#pragma unroll
    for (int c = 0; c < 2; ++c) {
      if ((unsigned)js[c] >= (unsigned)WD) continue;
      unsigned u = *(const unsigned*)(M + (long)(is[a] * WD + js[c]) * ND +
                                      (kus[a] * 4 + kvs[c]) * CC + o);
      s0 += bf2f((unsigned short)(u & 0xffffu));
      s1 += bf2f((unsigned short)(u >> 16));
    }
  }
  unsigned outw = (unsigned)f2bf(0.25f * s0) | ((unsigned)f2bf(0.25f * s1) << 16);
  *(unsigned*)(ypre + ((long)b * NPIX + Y * WW + X) * CC + o) = outw;
}

// ---------------- pack conv weights as bf16 [oc][(u*3+v)*64+c] ----------------
__global__ void pack_w(const float* __restrict__ w1, const float* __restrict__ w2,
                       unsigned short* __restrict__ w1t, unsigned short* __restrict__ w2t) {
  int idx = blockIdx.x * 256 + threadIdx.x;      // < 2*CC*KC
  int sel = idx / (CC * KC);
  int r = idx % (CC * KC);
  int oc = r / KC, k = r % KC;
  int uv = k / CC, c = k % CC;
  const float* src = sel ? w2 : w1;
  float v = src[(long)(oc * CC + c) * 9 + uv];
  (sel ? w2t : w1t)[r] = f2bf(v);
}

// ---------------- host ----------------
extern "C" void kernel_launch(void* const* d_in, const int* in_sizes, int n_in,
                              void* d_out, int out_size, void* d_ws, size_t ws_size,
                              hipStream_t stream) {
  const float* f = (const float*)d_in[0];
  const float* bimg = (const float*)d_in[1];
  const float* mask = (const float*)d_in[2];
  const float* w1 = (const float*)d_in[3];
  const float* b1 = (const float*)d_in[4];
  const float* w2 = (const float*)d_in[5];
  const float* b2 = (const float*)d_in[6];
  float* out = (float*)d_out;
  float* offout = out + 4L * CC * NPIX;          // off region (written as float)

  char* w = (char*)d_ws;
  float* fdt = (float*)w;  w += 4L * LQ * CC * 4;
  float* bdt = (float*)w;  w += 4L * LQ * CC * 4;
  float* sqb = (float*)w;  w += 4L * LQ * 4;
  float* invn = (float*)w; w += 4L * LQ * 4;
  float* mmb = (float*)w;  w += 4L * LQ * 4;
  unsigned short* zpage = (unsigned short*)w; w += 256;   // zero page for OOB staging
  unsigned short* w1t = (unsigned short*)w; w += (long)CC * KC * 4;  // region fp32-sized
  unsigned short* w2t = (unsigned short*)w; w += (long)CC * KC * 4;
  unsigned short* ypre = (unsigned short*)w; w += 4L * NPIX * CC * 4;  // region fp32-sized

  size_t fixed = (size_t)(w - (char*)d_ws);
  size_t szS_full = (size_t)4 * LL * 4;
  size_t szS_seq = (size_t)LL * 4;
  size_t szM_full = (size_t)4 * LQ * ND * 4;     // fp32-sized region, bf16 used
  size_t szM_seq = (size_t)LQ * ND * 4;
  // layout: [fixed][R3 (P)][RM][R2 (G / fp8 overlays / ybf1)][pad]
  size_t need_full = fixed + szM_full + 2 * szS_full + 1024;
  bool full = (ws_size >= need_full);

  size_t szS = full ? szS_full : szS_seq;
  size_t szM = full ? szM_full : szM_seq;
  float* R3 = (float*)w;                         // P
  unsigned short* RM = (unsigned short*)(w + szS);
  float* R2 = (float*)(w + szS + szM);
  unsigned char* Abf = (unsigned char*)R2;       // fp8 post (4*LL bytes)
  unsigned char* Wbf = Abf + (full ? 4L * LL : LL);
  unsigned short* ybf1 = (unsigned short*)R2;    // post-deconv overlay (Abf dead then)

  long sS = full ? LL : 0;
  long sMe = full ? (long)LQ * ND : 0;           // ushort elements
  long sWd = full ? (long)ND * LQ : 0;           // bytes (fp8)
  long sAb = full ? LL : 0;                      // bytes (fp8)
  long sFD = (long)LQ * CC;
  int NB = full ? 4 : 1;
  int nIter = full ? 1 : 4;

  hipMemsetAsync(zpage, 0, 256, stream);
  pack_w<<<dim3(288), 256, 0, stream>>>(w1, w2, w1t, w2t);

  for (int itb = 0; itb < nIter; ++itb) {
    int bb = full ? 0 : itb;
    int Mtot = NB * NPIX;
    pack_fdbd<<<dim3(576, 1, NB), 256, 0, stream>>>(f, bimg, fdt, bdt, bb);
    sq_kernel<<<dim3(LQ, 1, NB), 64, 0, stream>>>(bdt, sqb, bb);
    prep_l<<<dim3(9, 1, NB), 256, 0, stream>>>(sqb, mask, invn, mmb, bb);
    // Gram matrix G = fdt * bdt^T  (K = 64, fp32, single-stage — argmax-sensitive)
    gram_gemm<<<dim3(LQ / 128, LQ / 128, NB), 256, 0, stream>>>(
        fdt + (long)bb * sFD, bdt + (long)bb * sFD, R2, sFD, sFD, sS);
    // 9-tap diagonal box-sum + inv-norm  (G in R2 -> P in R3), XCD-swizzled grid
    patchsum_row<<<dim3(LQ * NB), 192, 0, stream>>>(R2, R3, sS, invn, bb);
    // fused double fuse_conv + masked softmax + argmax + fp8 store (P -> Abf)
    fuse_softmax_row<<<dim3(LQ * NB), 192, 0, stream>>>(R3, sS, mmb, Abf, sAb, offout, bb);
    // deconv as MX-fp8 MFMA GEMM (64x128, BK=128, unit-scale K=128 instruction)
    pack_wd<<<dim3(9216, 1, NB), 256, 0, stream>>>(bimg, Wbf, sWd, bb);
    gemm_deconv<<<dim3(8 * (LQ / 64) * NB), 256, 0, stream>>>(
        Abf, Wbf, RM, LQ, sAb, sWd, sMe, LQ / 64);
    scatter_deconv<<<dim3(12, 96, NB), 256, 0, stream>>>(RM, sMe, ypre, bb);
    // conv1 -> conv2 as direct-conv bf16 MFMA GEMMs (32x64 tiles; bias+ELU fused)
    const unsigned short* src1 = ypre + (full ? 0 : (long)bb * NPIX * CC);
    gemm_conv<1><<<dim3(Mtot / 32), 128, 0, stream>>>(src1, w1t, ybf1, b1, zpage, bb);
    gemm_conv<2><<<dim3(Mtot / 32), 128, 0, stream>>>(ybf1, w2t, out, b2, zpage, bb);
  }
}

// Round 17
// 235.424 us; speedup vs baseline: 1.0655x; 1.0075x over previous
//
#include <hip/hip_runtime.h>
#include <math.h>

// ---------------- problem constants ----------------
constexpr int HD = 48, WD = 48, LQ = HD * WD;     // 2304 downsampled positions / patches
constexpr int CC = 64;                             // channels
constexpr int HH = 96, WW = 96, NPIX = HH * WW;    // 9216 full-res pixels
constexpr int KC = CC * 9;                         // 576 im2col K
constexpr int ND = 16 * CC;                        // 1024 deconv GEMM N
constexpr long LL = (long)LQ * LQ;                 // 5,308,416

typedef __attribute__((ext_vector_type(8))) short bf16x8;
typedef __attribute__((ext_vector_type(4))) float f32x4;
typedef __attribute__((ext_vector_type(8))) int i32x8;
// 4-byte-aligned float4 for unaligned-base tap loads (gfx9 dwordx4 needs only 4B align)
typedef float f32x4u __attribute__((ext_vector_type(4), aligned(4)));

static __device__ __forceinline__ float eluf(float x) {
  return x > 0.f ? x : expm1f(x);
}
static __device__ __forceinline__ unsigned short f2bf(float x) {
  unsigned u = __float_as_uint(x);
  unsigned r = (u + 0x7fffu + ((u >> 16) & 1u)) >> 16;
  return (unsigned short)r;
}
static __device__ __forceinline__ float bf2f(unsigned short h) {
  return __uint_as_float((unsigned)h << 16);
}
// bijective XCD swizzle (m204): consecutive outputs land on one XCD
static __device__ __forceinline__ int xcd_swz(int bid, int nwg) {
  int q = nwg >> 3, r8 = nwg & 7;
  int xcd = bid & 7, idx = bid >> 3;
  return (xcd < r8 ? xcd * (q + 1) : r8 * (q + 1) + (xcd - r8) * q) + idx;
}

// ---------------- pack downsampled f/b as [q][c] ----------------
__global__ void pack_fdbd(const float* __restrict__ f, const float* __restrict__ bimg,
                          float* __restrict__ fdt, float* __restrict__ bdt, int batchBase) {
  int b = batchBase + blockIdx.z;
  int idx = blockIdx.x * 256 + threadIdx.x;      // < CC*LQ = 147456
  int c = idx / LQ, r = idx % LQ;
  int y = r / WD, x = r % WD;
  long src = ((long)(b * CC + c) * HH + 2 * y) * WW + 2 * x;
  long dst = (long)b * LQ * CC + (long)r * CC + c;
  fdt[dst] = f[src];
  bdt[dst] = bimg[src];
}

// ---------------- per-position squared-channel sums ----------------
__global__ void sq_kernel(const float* __restrict__ bdt, float* __restrict__ sq, int batchBase) {
  int b = batchBase + blockIdx.z;
  int q = blockIdx.x;
  int c = threadIdx.x;                            // 64 = one wave
  float v = bdt[(long)b * LQ * CC + (long)q * CC + c];
  v *= v;
  for (int off = 32; off; off >>= 1) v += __shfl_down(v, off);
  if (c == 0) sq[b * LQ + q] = v;
}

// ---------------- inv patch norms + valid-mask mm ----------------
__global__ void prep_l(const float* __restrict__ sq, const float* __restrict__ mask,
                       float* __restrict__ invn, float* __restrict__ mmb, int batchBase) {
  int b = batchBase + blockIdx.z;
  int l = blockIdx.x * 256 + threadIdx.x;        // < LQ exactly (grid 9)
  int li = l / WD, lj = l % WD;
  float ss = 0.f, mv = 0.f;
  for (int du = -1; du <= 1; ++du)
    for (int dv = -1; dv <= 1; ++dv) {
      int yy = li + du, xx = lj + dv;
      if ((unsigned)yy < (unsigned)HD && (unsigned)xx < (unsigned)WD) {
        ss += sq[b * LQ + yy * WD + xx];
        mv += mask[b * LQ + yy * WD + xx];
      }
    }
  invn[b * LQ + l] = 1.f / fmaxf(sqrtf(ss), 1e-4f);
  mmb[b * LQ + l] = (mv == 0.f) ? 1.f : 0.f;
}

// ---------------- fp32 Gram GEMM: G = fdt * bdt^T, K=64 single-stage ---------------
// BM=64 retile: LDS 48KB (As 16K + Bs 32K) -> 3 blocks/CU (was 2 at 64KB), 648
// blocks/batch. Per-output kk-ascending accumulation with identical a/b values
// -> bit-identical G (argmax-safe). B-read keeps the conflict-free column split.
__global__ __launch_bounds__(256) void gram_gemm(
    const float* __restrict__ A, const float* __restrict__ B, float* __restrict__ C,
    long sA, long sB, long sC) {
  constexpr int BM = 64, BN = 128, TM = 4, BK = 64;
  __shared__ float As[BK][BM];
  __shared__ float Bs[BK][BN];
  const int z = blockIdx.z;
  A += (long)z * sA;
  B += (long)z * sB;
  C += (long)z * sC;
  const int tn0 = blockIdx.x * BN;
  const int tm0 = blockIdx.y * BM;
  const int tid = threadIdx.x;
  const int tx = tid & 15, ty = tid >> 4;
#pragma unroll
  for (int s = 0; s < 4; ++s) {
    int idx = tid + s * 256;                     // < 1024
    int row = idx & 63;
    int k4 = idx >> 6;
    float4 v = *(const float4*)(A + (long)(tm0 + row) * CC + k4 * 4);
    As[k4 * 4 + 0][row] = v.x;
    As[k4 * 4 + 1][row] = v.y;
    As[k4 * 4 + 2][row] = v.z;
    As[k4 * 4 + 3][row] = v.w;
  }
#pragma unroll
  for (int s = 0; s < 8; ++s) {
    int idx = tid + s * 256;                     // < 2048
    int row = idx & 127;
    int k4 = idx >> 7;
    float4 u = *(const float4*)(B + (long)(tn0 + row) * CC + k4 * 4);
    Bs[k4 * 4 + 0][row] = u.x;
    Bs[k4 * 4 + 1][row] = u.y;
    Bs[k4 * 4 + 2][row] = u.z;
    Bs[k4 * 4 + 3][row] = u.w;
  }
  __syncthreads();
  float acc[TM][8];
#pragma unroll
  for (int m = 0; m < TM; ++m)
#pragma unroll
    for (int n = 0; n < 8; ++n) acc[m][n] = 0.f;
#pragma unroll 4
  for (int kk = 0; kk < BK; ++kk) {
    float a[TM], b[8];
    *(float4*)&a[0] = *(const float4*)&As[kk][ty * TM];       // 16-lane broadcast
    *(float4*)&b[0] = *(const float4*)&Bs[kk][tx * 4];        // 16 lanes x 16B stride
    *(float4*)&b[4] = *(const float4*)&Bs[kk][64 + tx * 4];   // -> conflict-free
#pragma unroll
    for (int m = 0; m < TM; ++m)
#pragma unroll
      for (int n = 0; n < 8; ++n) acc[m][n] = fmaf(a[m], b[n], acc[m][n]);
  }
#pragma unroll
  for (int m = 0; m < TM; ++m) {
    long row = tm0 + ty * TM + m;
    *(float4*)(C + row * LQ + tn0 + tx * 4) =
        make_float4(acc[m][0], acc[m][1], acc[m][2], acc[m][3]);
    *(float4*)(C + row * LQ + tn0 + 64 + tx * 4) =
        make_float4(acc[m][4], acc[m][5], acc[m][6], acc[m][7]);
  }
}

// ---------------- deconv MX-fp8 MFMA GEMM, 64x128 tile, BK=128, 2-phase dbuf -------
__global__ __launch_bounds__(256) void gemm_deconv(
    const unsigned char* __restrict__ A, const unsigned char* __restrict__ B,
    unsigned short* __restrict__ C, int K, long sA, long sB, long sC, int tilesY) {
  int swz = xcd_swz(blockIdx.x, gridDim.x);
  int perz = tilesY * 8;
  int z = swz / perz, t2 = swz - z * perz;
  int ty = t2 >> 3, tx = t2 & 7;
  A += (long)z * sA;
  B += (long)z * sB;
  C += (long)z * sC;
  const int tid = threadIdx.x;
  const int wave = tid >> 6, lane = tid & 63;
  const int wr = wave >> 1, wc = wave & 1;
  const int tm0 = ty * 64, tn0 = tx * 128;
  __shared__ unsigned char As[2][64 * 128];      // 8KB/buf
  __shared__ unsigned char Bs[2][128 * 128];     // 16KB/buf
  f32x4 acc[2][4] = {};

  int aRow[2], aCol[2], aDst[2];
#pragma unroll
  for (int t = 0; t < 2; ++t) {
    int o = t * 4096 + tid * 16;
    int row = o >> 7;
    aRow[t] = row;
    aCol[t] = (o & 127) ^ ((row & 7) << 4);      // byte == element offset
    aDst[t] = t * 4096 + wave * 1024;            // byte, wave-uniform
  }
  int bRow[4], bCol[4], bDst[4];
#pragma unroll
  for (int t = 0; t < 4; ++t) {
    int o = t * 4096 + tid * 16;
    int row = o >> 7;
    bRow[t] = row;
    bCol[t] = (o & 127) ^ ((row & 7) << 4);
    bDst[t] = t * 4096 + wave * 1024;
  }

#define STAGE_DC(buf, k0)                                                             \
  do {                                                                                \
    _Pragma("unroll") for (int t = 0; t < 2; ++t)                                     \
        __builtin_amdgcn_global_load_lds(                                             \
            (const __attribute__((address_space(1))) void*)(A +                       \
                (long)(tm0 + aRow[t]) * K + (k0) + aCol[t]),                          \
            (__attribute__((address_space(3))) void*)((char*)&As[buf][0] + aDst[t]),  \
            16, 0, 0);                                                                \
    _Pragma("unroll") for (int t = 0; t < 4; ++t)                                     \
        __builtin_amdgcn_global_load_lds(                                             \
            (const __attribute__((address_space(1))) void*)(B +                       \
                (long)(tn0 + bRow[t]) * K + (k0) + bCol[t]),                          \
            (__attribute__((address_space(3))) void*)((char*)&Bs[buf][0] + bDst[t]),  \
            16, 0, 0);                                                                \
  } while (0)

  STAGE_DC(0, 0);
  asm volatile("s_waitcnt vmcnt(0)");
  __builtin_amdgcn_s_barrier();
  int cur = 0;
  for (int k0 = 0; k0 < K; k0 += 128) {          // 18 steps
    if (k0 + 128 < K) STAGE_DC(cur ^ 1, k0 + 128);
    {
      const int o0 = (lane >> 4) << 5;           // 0,32,64,96
      i32x8 av[2], bv[4];
#pragma unroll
      for (int m = 0; m < 2; ++m) {
        int row = wr * 32 + m * 16 + (lane & 15);
        const unsigned char* base = &As[cur][0] + row * 128;
        int sw = (row & 7) << 4;
        *(uint4*)&av[m] = *(const uint4*)(base + (o0 ^ sw));
        *((uint4*)&av[m] + 1) = *(const uint4*)(base + ((o0 + 16) ^ sw));
      }
#pragma unroll
      for (int n = 0; n < 4; ++n) {
        int row = wc * 64 + n * 16 + (lane & 15);
        const unsigned char* base = &Bs[cur][0] + row * 128;
        int sw = (row & 7) << 4;
        *(uint4*)&bv[n] = *(const uint4*)(base + (o0 ^ sw));
        *((uint4*)&bv[n] + 1) = *(const uint4*)(base + ((o0 + 16) ^ sw));
      }
#pragma unroll
      for (int m = 0; m < 2; ++m)
#pragma unroll
        for (int n = 0; n < 4; ++n)
          acc[m][n] = __builtin_amdgcn_mfma_scale_f32_16x16x128_f8f6f4(
              av[m], bv[n], acc[m][n], 0, 0, 0, 0x7f7f7f7f, 0, 0x7f7f7f7f);
    }
    asm volatile("s_waitcnt vmcnt(0) lgkmcnt(0)" ::: "memory");
    __builtin_amdgcn_sched_barrier(0);
    __builtin_amdgcn_s_barrier();
    cur ^= 1;
  }
#undef STAGE_DC
  // C/D layout: col=lane&15, row=(lane>>4)*4+j  (shape-determined); bf16 store
#pragma unroll
  for (int m = 0; m < 2; ++m)
#pragma unroll
    for (int n = 0; n < 4; ++n) {
      int col = tn0 + wc * 64 + n * 16 + (lane & 15);
      int rb = tm0 + wr * 32 + m * 16 + ((lane >> 4) << 2);
#pragma unroll
      for (int j = 0; j < 4; ++j)
        C[(long)(rb + j) * ND + col] = f2bf(acc[m][n][j]);
    }
}

// ---------------- direct-conv bf16 MFMA GEMM: 32 pixels x 64 oc, K=9x64 -----------
template <int EPI>
__global__ __launch_bounds__(128) void gemm_conv(
    const unsigned short* __restrict__ A, const unsigned short* __restrict__ Bw,
    void* __restrict__ Cv, const float* __restrict__ bias,
    const unsigned short* __restrict__ zp, int batchBase) {
  __shared__ unsigned short As[2][32 * 64];
  __shared__ unsigned short Bs[2][64 * 64];
  const int tid = threadIdx.x;
  const int wave = tid >> 6, lane = tid & 63;
  const int tm0 = xcd_swz(blockIdx.x, gridDim.x) * 32;
  f32x4 acc[2][2] = {};
  int aRow[2], aColB[2], aDst[2], py[2], px[2];
  long pb[2];
#pragma unroll
  for (int t = 0; t < 2; ++t) {
    int o = t * 2048 + tid * 16;
    int row = o >> 7;
    aRow[t] = row;
    aColB[t] = (o & 127) ^ ((row & 7) << 4);
    aDst[t] = t * 2048 + wave * 1024;
    int m = tm0 + row;
    int bl = m / NPIX, r = m - bl * NPIX;
    py[t] = r / WW;
    px[t] = r - py[t] * WW;
    pb[t] = (long)bl * NPIX;
  }
  int bRow[4], bColE[4], bDst[4];
#pragma unroll
  for (int t = 0; t < 4; ++t) {
    int o = t * 2048 + tid * 16;
    int row = o >> 7;
    bRow[t] = row;
    bColE[t] = ((o & 127) ^ ((row & 7) << 4)) >> 1;
    bDst[t] = t * 2048 + wave * 1024;
  }
#define STAGE_CV(buf, uv)                                                              \
  do {                                                                                 \
    int u_ = (uv) / 3, v_ = (uv) - u_ * 3;                                             \
    _Pragma("unroll") for (int t = 0; t < 2; ++t) {                                    \
      int yy = py[t] + u_ - 1, xx = px[t] + v_ - 1;                                    \
      const unsigned short* src =                                                      \
          ((unsigned)yy < (unsigned)HH && (unsigned)xx < (unsigned)WW)                 \
              ? A + (pb[t] + yy * WW + xx) * CC + (aColB[t] >> 1)                      \
              : zp;                                                                    \
      __builtin_amdgcn_global_load_lds(                                                \
          (const __attribute__((address_space(1))) void*)src,                          \
          (__attribute__((address_space(3))) void*)((char*)&As[buf][0] + aDst[t]),     \
          16, 0, 0);                                                                   \
    }                                                                                  \
    _Pragma("unroll") for (int t = 0; t < 4; ++t)                                      \
        __builtin_amdgcn_global_load_lds(                                              \
            (const __attribute__((address_space(1))) void*)(Bw +                       \
                (long)bRow[t] * KC + (uv)*64 + bColE[t]),                              \
            (__attribute__((address_space(3))) void*)((char*)&Bs[buf][0] + bDst[t]),   \
            16, 0, 0);                                                                 \
  } while (0)

  STAGE_CV(0, 0);
  asm volatile("s_waitcnt vmcnt(0)");
  __builtin_amdgcn_s_barrier();
  int cur = 0;
  for (int uv = 0; uv < 9; ++uv) {
    if (uv + 1 < 9) STAGE_CV(cur ^ 1, uv + 1);
#pragma unroll
    for (int ks = 0; ks < 2; ++ks) {
      const int cbase = ks * 64 + ((lane >> 4) << 4);
      bf16x8 av[2], bv[2];
#pragma unroll
      for (int m = 0; m < 2; ++m) {
        int row = m * 16 + (lane & 15);
        av[m] = *(const bf16x8*)((const char*)&As[cur][0] + row * 128 + (cbase ^ ((row & 7) << 4)));
      }
#pragma unroll
      for (int n = 0; n < 2; ++n) {
        int row = wave * 32 + n * 16 + (lane & 15);
        bv[n] = *(const bf16x8*)((const char*)&Bs[cur][0] + row * 128 + (cbase ^ ((row & 7) << 4)));
      }
#pragma unroll
      for (int m = 0; m < 2; ++m)
#pragma unroll
        for (int n = 0; n < 2; ++n)
          acc[m][n] = __builtin_amdgcn_mfma_f32_16x16x32_bf16(av[m], bv[n], acc[m][n], 0, 0, 0);
    }
    asm volatile("s_waitcnt vmcnt(0) lgkmcnt(0)" ::: "memory");
    __builtin_amdgcn_sched_barrier(0);
    __builtin_amdgcn_s_barrier();
    cur ^= 1;
  }
#undef STAGE_CV
#pragma unroll
  for (int m = 0; m < 2; ++m)
#pragma unroll
    for (int n = 0; n < 2; ++n) {
      int col = wave * 32 + n * 16 + (lane & 15);
      float bb_ = bias[col];
      int rb = tm0 + m * 16 + ((lane >> 4) << 2);
      if (EPI == 1) {
#pragma unroll
        for (int j = 0; j < 4; ++j) {
          float v = eluf(acc[m][n][j] + bb_);
          ((unsigned short*)Cv)[(long)(rb + j) * CC + col] = f2bf(v);
        }
      } else {
        int bl = batchBase + rb / NPIX;
        int r = rb % NPIX;
        float4 o4 = make_float4(eluf(acc[m][n][0] + bb_), eluf(acc[m][n][1] + bb_),
                                eluf(acc[m][n][2] + bb_), eluf(acc[m][n][3] + bb_));
        *(float4*)((float*)Cv + ((long)(bl * CC + col)) * NPIX + r) = o4;
      }
    }
}

// ---------------- 9-tap diagonal patch box-sum + inv-norm (lane-contiguous f4) ----
__global__ __launch_bounds__(192) void patchsum_row(
    const float* __restrict__ G0, float* __restrict__ O0, long sBuf,
    const float* __restrict__ invn, int batchBase) {
  int swz = xcd_swz(blockIdx.x, gridDim.x);
  int z = swz / LQ, p = swz - z * LQ;
  const float* G = G0 + (long)z * sBuf;
  float* O = O0 + (long)z * sBuf;
  int i = p / WD, j = p - i * WD;
  int t = threadIdx.x;
#pragma unroll
  for (int ps = 0; ps < 3; ++ps) {
    int q = 4 * (ps * 192 + t);
    int li = q / WD, lj = q - li * WD;
    float a0 = 0.f, a1 = 0.f, a2 = 0.f, a3 = 0.f;
#pragma unroll
    for (int du = -1; du <= 1; ++du) {
      if ((unsigned)(i + du) >= (unsigned)HD) continue;    // block-uniform
      if ((unsigned)(li + du) >= (unsigned)HD) continue;   // thread-level
#pragma unroll
      for (int dv = -1; dv <= 1; ++dv) {
        if ((unsigned)(j + dv) >= (unsigned)WD) continue;  // block-uniform
        int D = du * WD + dv;
        f32x4u v = *(const f32x4u*)(G + (long)(p + D) * LQ + (q + D));
        if (dv < 0) {
          if (lj > 0) a0 += v.x;
          a1 += v.y; a2 += v.z; a3 += v.w;
        } else if (dv > 0) {
          a0 += v.x; a1 += v.y; a2 += v.z;
          if (lj < 44) a3 += v.w;
        } else {
          a0 += v.x; a1 += v.y; a2 += v.z; a3 += v.w;
        }
      }
    }
    f32x4 n4 = *(const f32x4*)(invn + (long)(batchBase + z) * LQ + q);
    *(float4*)(O + (long)p * LQ + q) =
        make_float4(a0 * n4.x, a1 * n4.y, a2 * n4.z, a3 * n4.w);
  }
}

// ---------------- fused fuse_conv1+fuse_conv2 + masked softmax + argmax + fp8 ----
__global__ __launch_bounds__(192) void fuse_softmax_row(
    const float* __restrict__ P0, long sBuf, const float* __restrict__ mmb,
    unsigned char* __restrict__ Ab, long sAb, float* __restrict__ offout, int batchBase) {
  int swz = xcd_swz(blockIdx.x, gridDim.x);
  int z = swz / LQ, p = swz - z * LQ;
  const float* P = P0 + (long)z * sBuf;
  int b = batchBase + z;
  int i = p / WD, j = p - i * WD;
  int t = threadIdx.x;
  int pp = j * HD + i;

  int rr[3];
  bool dok[3];
#pragma unroll
  for (int dd = 0; dd < 3; ++dd) {
    int a = pp + dd - 1;
    dok[dd] = ((unsigned)a < (unsigned)LQ);
    rr[dd] = dok[dd] ? (a % HD) * WD + (a / HD) : 0;
  }

  float zv[3][4], mv[3][4];
  float mx = -1e30f;
#pragma unroll
  for (int ps = 0; ps < 3; ++ps) {
    int q = 4 * (ps * 192 + t);
    int li = q / WD, lj = q - li * WD;
    float a0 = 0.f, a1 = 0.f, a2 = 0.f, a3 = 0.f;
#pragma unroll
    for (int dd = 0; dd < 3; ++dd) {
      if (!dok[dd]) continue;
      int r = rr[dd];
      bool rm = (r > 0), rp = (r < LQ - 1);
      const float* rowp = P + (long)r * LQ;
      int lid = li + dd - 1;
      if ((unsigned)lid < (unsigned)HD) {                  // main path
        long cb = (long)lid * WD + lj;
        f32x4u v0 = *(const f32x4u*)(rowp + cb);
        f32x4u vm = {0.f, 0.f, 0.f, 0.f}, vp = {0.f, 0.f, 0.f, 0.f};
        if (rm) vm = *(const f32x4u*)(rowp - LQ + cb - 1);
        if (rp) vp = *(const f32x4u*)(rowp + LQ + cb + 1);
        { float s = v0.x; if (rm && cb > 0) s += vm.x; if (rp) s += vp.x; a0 += s; }
        { float s = v0.y; if (rm) s += vm.y; if (rp) s += vp.y; a1 += s; }
        { float s = v0.z; if (rm) s += vm.z; if (rp) s += vp.z; a2 += s; }
        { float s = v0.w; if (rm) s += vm.w; if (rp && cb < LQ - 4) s += vp.w; a3 += s; }
      } else if (lid == -1) {                              // wrap-low (li==0, d=-1)
        long cb = (long)(HD - 1) * WD + lj - 1;
        f32x4u v0 = *(const f32x4u*)(rowp + cb);
        f32x4u vm = {0.f, 0.f, 0.f, 0.f}, vp = {0.f, 0.f, 0.f, 0.f};
        if (rm) vm = *(const f32x4u*)(rowp - LQ + cb - 1);
        if (rp) vp = *(const f32x4u*)(rowp + LQ + cb + 1);
        if (lj >= 1) { float s = v0.x; if (rm) s += vm.x; if (rp) s += vp.x; a0 += s; }
        { float s = v0.y; if (rm) s += vm.y; if (rp) s += vp.y; a1 += s; }
        { float s = v0.z; if (rm) s += vm.z; if (rp) s += vp.z; a2 += s; }
        { float s = v0.w; if (rm) s += vm.w; if (rp) s += vp.w; a3 += s; }
      } else {                                             // lid == HD (li==47, d=+1)
        long cb = (long)lj + 1;
        f32x4u v0 = *(const f32x4u*)(rowp + cb);
        f32x4u vm = {0.f, 0.f, 0.f, 0.f}, vp = {0.f, 0.f, 0.f, 0.f};
        if (rm) vm = *(const f32x4u*)(rowp - LQ + cb - 1);
        if (rp) vp = *(const f32x4u*)(rowp + LQ + cb + 1);
        { float s = v0.x; if (rm) s += vm.x; if (rp) s += vp.x; a0 += s; }
        { float s = v0.y; if (rm) s += vm.y; if (rp) s += vp.y; a1 += s; }
        { float s = v0.z; if (rm) s += vm.z; if (rp) s += vp.z; a2 += s; }
        if (lj < 44) { float s = v0.w; if (rm) s += vm.w; if (rp) s += vp.w; a3 += s; }
      }
    }
    f32x4 m4 = *(const f32x4*)(mmb + (long)b * LQ + q);
    mv[ps][0] = m4.x; mv[ps][1] = m4.y; mv[ps][2] = m4.z; mv[ps][3] = m4.w;
    zv[ps][0] = (m4.x != 0.f) ? a0 * 10.f : 0.f;
    zv[ps][1] = (m4.y != 0.f) ? a1 * 10.f : 0.f;
    zv[ps][2] = (m4.z != 0.f) ? a2 * 10.f : 0.f;
    zv[ps][3] = (m4.w != 0.f) ? a3 * 10.f : 0.f;
#pragma unroll
    for (int e = 0; e < 4; ++e) mx = fmaxf(mx, zv[ps][e]);
  }

  // 3-wave shuffle reductions
  __shared__ float s_m[3], s_s[3], s_av[3];
  __shared__ int s_ai[3];
  int wv = t >> 6;
#pragma unroll
  for (int off = 32; off; off >>= 1) mx = fmaxf(mx, __shfl_xor(mx, off));
  if ((t & 63) == 0) s_m[wv] = mx;
  __syncthreads();
  float M = fmaxf(s_m[0], fmaxf(s_m[1], s_m[2]));

  float sum = 0.f;
  float ev[3][4];
#pragma unroll
  for (int ps = 0; ps < 3; ++ps)
#pragma unroll
    for (int e = 0; e < 4; ++e) {
      ev[ps][e] = __expf(zv[ps][e] - M);         // native v_exp_f32 (monotone)
      sum += ev[ps][e];
    }
#pragma unroll
  for (int off = 32; off; off >>= 1) sum += __shfl_xor(sum, off);
  if ((t & 63) == 0) s_s[wv] = sum;
  __syncthreads();
  float inv = 1.f / (s_s[0] + s_s[1] + s_s[2]);

  float bv = -1.f;
  int bi = 0;
  unsigned char* arow = Ab + (long)z * sAb + (long)p * LQ;
#pragma unroll
  for (int ps = 0; ps < 3; ++ps) {
    int q = 4 * (ps * 192 + t);
    float post0 = (mv[ps][0] != 0.f) ? ev[ps][0] * inv : 0.f;
    float post1 = (mv[ps][1] != 0.f) ? ev[ps][1] * inv : 0.f;
    float post2 = (mv[ps][2] != 0.f) ? ev[ps][2] * inv : 0.f;
    float post3 = (mv[ps][3] != 0.f) ? ev[ps][3] * inv : 0.f;
    if (post0 > bv) { bv = post0; bi = q; }
    if (post1 > bv) { bv = post1; bi = q + 1; }
    if (post2 > bv) { bv = post2; bi = q + 2; }
    if (post3 > bv) { bv = post3; bi = q + 3; }
    int pk = 0;
    pk = __builtin_amdgcn_cvt_pk_fp8_f32(post0, post1, pk, false);
    pk = __builtin_amdgcn_cvt_pk_fp8_f32(post2, post3, pk, true);
    *(unsigned*)(arow + q) = (unsigned)pk;       // q % 4 == 0 -> aligned
  }
#pragma unroll
  for (int off = 32; off; off >>= 1) {
    float ov = __shfl_xor(bv, off);
    int oi = __shfl_xor(bi, off);
    if (ov > bv || (ov == bv && oi < bi)) { bv = ov; bi = oi; }
  }
  if ((t & 63) == 0) { s_av[wv] = bv; s_ai[wv] = bi; }
  __syncthreads();
  if (t == 0) {
    float fbv = s_av[0];
    int fbi = s_ai[0];
    for (int k = 1; k < 3; ++k) {
      if (s_av[k] > fbv || (s_av[k] == fbv && s_ai[k] < fbi)) { fbv = s_av[k]; fbi = s_ai[k]; }
    }
    offout[((long)b * 2 + 0) * LQ + p] = (float)(fbi / WD - i);
    offout[((long)b * 2 + 1) * LQ + p] = (float)(fbi % WD - j);
  }
}

// ---------------- pack deconv weights WdT[(ku*4+kv)*64+o][l] as fp8 e4m3 -----------
__global__ void pack_wd(const float* __restrict__ bimg, unsigned char* __restrict__ WdT,
                        long sWd, int batchBase) {
  int z = blockIdx.z;
  int b = batchBase + z;
  int idx = blockIdx.x * 256 + threadIdx.x;      // < ND*LQ
  int n = idx / LQ, l = idx - n * LQ;
  int o = n % CC, kuv = n / CC, ku = kuv >> 2, kv = kuv & 3;
  int li = l / WD, lj = l % WD;
  int yy = 2 * li + ku - 1, xx = 2 * lj + kv - 1;
  float v = 0.f;
  if ((unsigned)yy < (unsigned)HH && (unsigned)xx < (unsigned)WW)
    v = bimg[((long)(b * CC + o) * HH + yy) * WW + xx];
  int pk = __builtin_amdgcn_cvt_pk_fp8_f32(v, 0.f, 0, false);
  WdT[(long)z * sWd + idx] = (unsigned char)(pk & 0xff);
}

// ---------------- scatter deconv GEMM result (bf16) into bf16 HWC y_pre ------------
__global__ void scatter_deconv(const unsigned short* __restrict__ Mo, long sMo,
                               unsigned short* __restrict__ ypre, int batchBase) {
  int z = blockIdx.z;
  int b = batchBase + z;
  int o = (threadIdx.x & 31) * 2, xq = threadIdx.x >> 5;
  int X = blockIdx.x * 8 + xq, Y = blockIdx.y;   // grid (12, 96, NB)
  const unsigned short* M = Mo + (long)z * sMo;
  int iA, kuA, iB, kuB;
  if (Y & 1) { iA = (Y + 1) >> 1; kuA = 0; iB = (Y - 1) >> 1; kuB = 2; }
  else       { iA = Y >> 1;       kuA = 1; iB = (Y >> 1) - 1; kuB = 3; }
  int jA, kvA, jB, kvB;
  if (X & 1) { jA = (X + 1) >> 1; kvA = 0; jB = (X - 1) >> 1; kvB = 2; }
  else       { jA = X >> 1;       kvA = 1; jB = (X >> 1) - 1; kvB = 3; }
  int is[2] = {iA, iB}, kus[2] = {kuA, kuB};
  int js[2] = {jA, jB}, kvs[2] = {kvA, kvB};
  float s0 = 0.f, s1 = 0.f;
#pragma unroll
  for (int a = 0; a < 2; ++a) {
    if ((unsigned)is[a] >= (unsigned)HD) continue;
#pragma unroll
    for (int c = 0; c < 2; ++c) {
      if ((unsigned)js[c] >= (unsigned)WD) continue;
      unsigned u = *(const unsigned*)(M + (long)(is[a] * WD + js[c]) * ND +
                                      (kus[a] * 4 + kvs[c]) * CC + o);
      s0 += bf2f((unsigned short)(u & 0xffffu));
      s1 += bf2f((unsigned short)(u >> 16));
    }
  }
  unsigned outw = (unsigned)f2bf(0.25f * s0) | ((unsigned)f2bf(0.25f * s1) << 16);
  *(unsigned*)(ypre + ((long)b * NPIX + Y * WW + X) * CC + o) = outw;
}

// ---------------- pack conv weights as bf16 [oc][(u*3+v)*64+c] ----------------
__global__ void pack_w(const float* __restrict__ w1, const float* __restrict__ w2,
                       unsigned short* __restrict__ w1t, unsigned short* __restrict__ w2t) {
  int idx = blockIdx.x * 256 + threadIdx.x;      // < 2*CC*KC
  int sel = idx / (CC * KC);
  int r = idx % (CC * KC);
  int oc = r / KC, k = r % KC;
  int uv = k / CC, c = k % CC;
  const float* src = sel ? w2 : w1;
  float v = src[(long)(oc * CC + c) * 9 + uv];
  (sel ? w2t : w1t)[r] = f2bf(v);
}

// ---------------- host ----------------
extern "C" void kernel_launch(void* const* d_in, const int* in_sizes, int n_in,
                              void* d_out, int out_size, void* d_ws, size_t ws_size,
                              hipStream_t stream) {
  const float* f = (const float*)d_in[0];
  const float* bimg = (const float*)d_in[1];
  const float* mask = (const float*)d_in[2];
  const float* w1 = (const float*)d_in[3];
  const float* b1 = (const float*)d_in[4];
  const float* w2 = (const float*)d_in[5];
  const float* b2 = (const float*)d_in[6];
  float* out = (float*)d_out;
  float* offout = out + 4L * CC * NPIX;          // off region (written as float)

  char* w = (char*)d_ws;
  float* fdt = (float*)w;  w += 4L * LQ * CC * 4;
  float* bdt = (float*)w;  w += 4L * LQ * CC * 4;
  float* sqb = (float*)w;  w += 4L * LQ * 4;
  float* invn = (float*)w; w += 4L * LQ * 4;
  float* mmb = (float*)w;  w += 4L * LQ * 4;
  unsigned short* zpage = (unsigned short*)w; w += 256;   // zero page for OOB staging
  unsigned short* w1t = (unsigned short*)w; w += (long)CC * KC * 4;  // region fp32-sized
  unsigned short* w2t = (unsigned short*)w; w += (long)CC * KC * 4;
  unsigned short* ypre = (unsigned short*)w; w += 4L * NPIX * CC * 4;  // region fp32-sized

  size_t fixed = (size_t)(w - (char*)d_ws);
  size_t szS_full = (size_t)4 * LL * 4;
  size_t szS_seq = (size_t)LL * 4;
  size_t szM_full = (size_t)4 * LQ * ND * 4;     // fp32-sized region, bf16 used
  size_t szM_seq = (size_t)LQ * ND * 4;
  // layout: [fixed][R3 (P)][RM][R2 (G / fp8 overlays / ybf1)][pad]
  size_t need_full = fixed + szM_full + 2 * szS_full + 1024;
  bool full = (ws_size >= need_full);

  size_t szS = full ? szS_full : szS_seq;
  size_t szM = full ? szM_full : szM_seq;
  float* R3 = (float*)w;                         // P
  unsigned short* RM = (unsigned short*)(w + szS);
  float* R2 = (float*)(w + szS + szM);
  unsigned char* Abf = (unsigned char*)R2;       // fp8 post (4*LL bytes)
  unsigned char* Wbf = Abf + (full ? 4L * LL : LL);
  unsigned short* ybf1 = (unsigned short*)R2;    // post-deconv overlay (Abf dead then)

  long sS = full ? LL : 0;
  long sMe = full ? (long)LQ * ND : 0;           // ushort elements
  long sWd = full ? (long)ND * LQ : 0;           // bytes (fp8)
  long sAb = full ? LL : 0;                      // bytes (fp8)
  long sFD = (long)LQ * CC;
  int NB = full ? 4 : 1;
  int nIter = full ? 1 : 4;

  hipMemsetAsync(zpage, 0, 256, stream);
  pack_w<<<dim3(288), 256, 0, stream>>>(w1, w2, w1t, w2t);

  for (int itb = 0; itb < nIter; ++itb) {
    int bb = full ? 0 : itb;
    int Mtot = NB * NPIX;
    pack_fdbd<<<dim3(576, 1, NB), 256, 0, stream>>>(f, bimg, fdt, bdt, bb);
    sq_kernel<<<dim3(LQ, 1, NB), 64, 0, stream>>>(bdt, sqb, bb);
    prep_l<<<dim3(9, 1, NB), 256, 0, stream>>>(sqb, mask, invn, mmb, bb);
    // Gram matrix G = fdt * bdt^T  (K = 64, fp32, single-stage — argmax-sensitive)
    gram_gemm<<<dim3(LQ / 128, LQ / 64, NB), 256, 0, stream>>>(
        fdt + (long)bb * sFD, bdt + (long)bb * sFD, R2, sFD, sFD, sS);
    // 9-tap diagonal box-sum + inv-norm  (G in R2 -> P in R3), XCD-swizzled grid
    patchsum_row<<<dim3(LQ * NB), 192, 0, stream>>>(R2, R3, sS, invn, bb);
    // fused double fuse_conv + masked softmax + argmax + fp8 store (P -> Abf)
    fuse_softmax_row<<<dim3(LQ * NB), 192, 0, stream>>>(R3, sS, mmb, Abf, sAb, offout, bb);
    // deconv as MX-fp8 MFMA GEMM (64x128, BK=128, unit-scale K=128 instruction)
    pack_wd<<<dim3(9216, 1, NB), 256, 0, stream>>>(bimg, Wbf, sWd, bb);
    gemm_deconv<<<dim3(8 * (LQ / 64) * NB), 256, 0, stream>>>(
        Abf, Wbf, RM, LQ, sAb, sWd, sMe, LQ / 64);
    scatter_deconv<<<dim3(12, 96, NB), 256, 0, stream>>>(RM, sMe, ypre, bb);
    // conv1 -> conv2 as direct-conv bf16 MFMA GEMMs (32x64 tiles; bias+ELU fused)
    const unsigned short* src1 = ypre + (full ? 0 : (long)bb * NPIX * CC);
    gemm_conv<1><<<dim3(Mtot / 32), 128, 0, stream>>>(src1, w1t, ybf1, b1, zpage, bb);
    gemm_conv<2><<<dim3(Mtot / 32), 128, 0, stream>>>(ybf1, w2t, out, b2, zpage, bb);
  }
}